// Round 5
// baseline (445.823 us; speedup 1.0000x reference)
//
#include <hip/hip_runtime.h>
#include <hip/hip_bf16.h>
#include <math.h>

// Problem constants
#define B_   64
#define T_   64
#define E_   512
#define DM   1024   // d_model
#define DI   2048   // d_inner
#define DS   16     // d_state
#define DTR  64     // dt_rank
#define M_   4096   // B*T rows

typedef __hip_bfloat16 bf16;
typedef __attribute__((ext_vector_type(8))) short bf16x8;   // 8 bf16 = 4 VGPRs
typedef __attribute__((ext_vector_type(4))) float f32x4;

__device__ __forceinline__ float b2f(short s) {
    return __uint_as_float(((unsigned)(unsigned short)s) << 16);
}

// ---------------------------------------------------------------------------
// bf16 MFMA GEMM: C[M x N] = act(A @ B + bias)
//   A  : bf16 (M x K) row-major, lda;  Bt : bf16 (N x K) row-major, ldb
// Block tile BM x BN (BK=32), 256 threads, 2x2 wave grid.
// A is staged via global_load_lds width=16 (linear [row][32] layout — the R4
// XOR swizzle regressed and is reverted). B is NOT staged: in the Bt layout a
// wave's B-fragment is a per-lane contiguous 16 B global read, so it goes
// global->VGPR with register double-buffering. This halves LDS port traffic
// (48 KB -> 24 KB per block-iter), which round-4 counters showed to be G1's
// binding resource (MfmaUtil ~18%, VALUBusy ~14%).
// ACT: 0 none, 1 relu, 2 softplus.
// SPLITK>1: gridDim.z-way K split, writes fp32 partials at z*M_*ldc.
// ---------------------------------------------------------------------------
template<int ACT, int OUTBF, int SPLITK, int BM, int BN>
__global__ __launch_bounds__(256) void gemm_mfma(
    const bf16* __restrict__ A, int lda,
    const bf16* __restrict__ Bt, int ldb,
    void* __restrict__ Cv, int ldc,
    const float* __restrict__ bias,
    int Ndim, int Kdim)
{
    __shared__ __align__(16) bf16 As[BM * 32];
    const int tid  = threadIdx.x;
    const int wave = tid >> 6;
    const int lane = tid & 63;
    const int bm = blockIdx.y * BM;
    const int bn = blockIdx.x * BN;
    // A staging: per issue, 64 lanes cover 16 rows x 4 k-chunks of 8 bf16
    const int lrow = lane >> 2;               // 0..15
    const int lkc  = (lane & 3) * 8;          // k element offset 0,8,16,24
    constexpr int NI = BM / 64;               // staging issues per wave
    // compute: 2x2 wave grid
    constexpr int WMT = BM / 32;              // 16-tiles per wave (M)
    constexpr int WNT = BN / 32;              // 16-tiles per wave (N)
    const int wm = (wave >> 1) * (BM / 2);
    const int wn = (wave & 1) * (BN / 2);
    const int fm = lane & 15;                 // fragment row/col
    const int fq = lane >> 4;                 // quad 0..3

    int kstart = 0, kend = Kdim;
    if (SPLITK > 1) {
        int chunk = Kdim / SPLITK;
        kstart = blockIdx.z * chunk;
        kend = kstart + chunk;
    }

    // Per-lane B row pointers (fixed): lane reads Bt[row][k + fq*8 .. +8]
    const bf16* bp[WNT];
    #pragma unroll
    for (int j = 0; j < WNT; ++j) {
        int row = bn + wn + j * 16 + fm;
        if (row >= Ndim) row = Ndim - 1;      // clamp; cols >= Ndim never stored
        bp[j] = Bt + (size_t)row * ldb + fq * 8;
    }

    f32x4 acc[WMT][WNT];
    #pragma unroll
    for (int i = 0; i < WMT; ++i)
        #pragma unroll
        for (int j = 0; j < WNT; ++j)
            acc[i][j] = (f32x4){0.f, 0.f, 0.f, 0.f};

    bf16x8 bcur[WNT], bnext[WNT];
    #pragma unroll
    for (int j = 0; j < WNT; ++j) bcur[j] = *(const bf16x8*)(bp[j] + kstart);

    for (int k0 = kstart; k0 < kend; k0 += 32) {
        // stage A tile (BM x 32) via async global->LDS
        #pragma unroll
        for (int i = 0; i < NI; ++i) {
            int rowbase = wave * (BM / 4) + i * 16;   // wave-uniform
            const bf16* ga = A + (size_t)(bm + rowbase + lrow) * lda + k0 + lkc;
            __builtin_amdgcn_global_load_lds(
                (const __attribute__((address_space(1))) void*)ga,
                (__attribute__((address_space(3))) void*)&As[rowbase * 32],
                16, 0, 0);
        }
        // prefetch next B fragments (global->VGPR, overlaps A staging)
        int kn = (k0 + 32 < kend) ? k0 + 32 : k0;
        #pragma unroll
        for (int j = 0; j < WNT; ++j) bnext[j] = *(const bf16x8*)(bp[j] + kn);
        __syncthreads();
        bf16x8 a[WMT];
        #pragma unroll
        for (int i = 0; i < WMT; ++i)
            a[i] = *(const bf16x8*)&As[(wm + i * 16 + fm) * 32 + fq * 8];
        #pragma unroll
        for (int i = 0; i < WMT; ++i)
            #pragma unroll
            for (int j = 0; j < WNT; ++j)
                acc[i][j] = __builtin_amdgcn_mfma_f32_16x16x32_bf16(
                    a[i], bcur[j], acc[i][j], 0, 0, 0);
        __syncthreads();
        #pragma unroll
        for (int j = 0; j < WNT; ++j) bcur[j] = bnext[j];
    }

    // Epilogue. C/D layout: col = lane&15, row = (lane>>4)*4 + r
    size_t zoff = (SPLITK > 1) ? (size_t)blockIdx.z * M_ * ldc : 0;
    #pragma unroll
    for (int i = 0; i < WMT; ++i) {
        int rowb = bm + wm + i * 16 + fq * 4;
        #pragma unroll
        for (int j = 0; j < WNT; ++j) {
            int col = bn + wn + j * 16 + fm;
            if (col < Ndim) {
                float bv = bias ? bias[col] : 0.f;
                #pragma unroll
                for (int r = 0; r < 4; ++r) {
                    float v = acc[i][j][r] + bv;
                    if (ACT == 1) v = fmaxf(v, 0.f);
                    if (ACT == 2) v = (v > 20.f) ? v : __logf(1.f + __expf(v));
                    size_t off = (size_t)(rowb + r) * ldc + col;
                    if (SPLITK > 1) ((float*)Cv)[zoff + off] = v;
                    else if (OUTBF) ((bf16*)Cv)[off] = __float2bfloat16(v);
                    else            ((float*)Cv)[off] = v;
                }
            }
        }
    }
}

// ---------------------------------------------------------------------------
// prep: one launch doing concat->bf16 (blocks [0,4096)) and all 5 weight
// transposes fp32(K,N) -> bf16(N,K) (32x32 LDS tiles, blocks [4096,11200)).
// ---------------------------------------------------------------------------
__global__ __launch_bounds__(256) void prep_kernel(
    const float* __restrict__ sp, const float* __restrict__ tp,
    bf16* __restrict__ xb,
    const float* __restrict__ W_in,  bf16* __restrict__ WinT,
    const float* __restrict__ W_x,   bf16* __restrict__ WxT,
    const float* __restrict__ W_dt,  bf16* __restrict__ WdT,
    const float* __restrict__ W_out, bf16* __restrict__ WoT,
    const float* __restrict__ W1,    bf16* __restrict__ W1T,
    const float* __restrict__ W2,    bf16* __restrict__ W2T)
{
    __shared__ float tile[32][33];
    const int b = blockIdx.x;
    const int tid = threadIdx.x;
    if (b < 4096) {
        // concat(spatial, temporal) -> xb (M_, 1024)
        int idx = b * 256 + tid;
        int row = idx >> 8;
        int c4 = (idx & 255) * 4;
        const float* src = (c4 < 512) ? (sp + (size_t)row * 512 + c4)
                                      : (tp + (size_t)row * 512 + (c4 - 512));
        float4 v = *(const float4*)src;
        bf16* dst = xb + (size_t)row * 1024 + c4;
        dst[0] = __float2bfloat16(v.x); dst[1] = __float2bfloat16(v.y);
        dst[2] = __float2bfloat16(v.z); dst[3] = __float2bfloat16(v.w);
        return;
    }
    const float* W; bf16* Wt; int K, N, tb;
    if      (b < 8192)  { W = W_in;  Wt = WinT; K = 1024; N = 4096; tb = b - 4096; }
    else if (b < 8384)  { W = W_x;   Wt = WxT;  K = 2048; N = 96;   tb = b - 8192; }
    else if (b < 8512)  { W = W_dt;  Wt = WdT;  K = 64;   N = 2048; tb = b - 8384; }
    else if (b < 10560) { W = W_out; Wt = WoT;  K = 2048; N = 1024; tb = b - 8512; }
    else if (b < 11072) { W = W1;    Wt = W1T;  K = 1024; N = 512;  tb = b - 10560; }
    else                { W = W2;    Wt = W2T;  K = 512;  N = 256;  tb = b - 11072; }
    int nb = N / 32;
    int bn = (tb % nb) * 32, bk = (tb / nb) * 32;
    int tx = tid & 31, ty = tid >> 5;
    #pragma unroll
    for (int i = 0; i < 32; i += 8)
        tile[ty + i][tx] = W[(size_t)(bk + ty + i) * N + bn + tx];
    __syncthreads();
    #pragma unroll
    for (int i = 0; i < 32; i += 8)
        Wt[(size_t)(bn + ty + i) * K + bk + tx] = __float2bfloat16(tile[tx][ty + i]);
}

// ---------------------------------------------------------------------------
// Causal depthwise conv (K=4) + bias + silu, bf16 in, bf16 out (for G2 only;
// the scan recomputes the fp32 conv inline). 4 channels per thread.
// ---------------------------------------------------------------------------
__global__ __launch_bounds__(256) void conv_silu_kernel(
    const bf16* __restrict__ xzb, const float* __restrict__ conv_w,
    const float* __restrict__ conv_b, bf16* __restrict__ xcb)
{
    int idx = blockIdx.x * 256 + threadIdx.x;   // over M_*DI/4
    int d4 = (idx & 511) * 4;                    // DI/4 = 512
    int bt = idx >> 9;
    int t = bt & (T_ - 1);
    float acc[4];
    #pragma unroll
    for (int j = 0; j < 4; ++j) acc[j] = conv_b[d4 + j];
    #pragma unroll
    for (int k = 0; k < 4; ++k) {
        int tt = t + k - 3;
        if (tt >= 0) {
            short4 xv4 = *(const short4*)&xzb[(size_t)(bt + k - 3) * 4096 + d4];
            acc[0] = fmaf(b2f(xv4.x), conv_w[(d4 + 0) * 4 + k], acc[0]);
            acc[1] = fmaf(b2f(xv4.y), conv_w[(d4 + 1) * 4 + k], acc[1]);
            acc[2] = fmaf(b2f(xv4.z), conv_w[(d4 + 2) * 4 + k], acc[2]);
            acc[3] = fmaf(b2f(xv4.w), conv_w[(d4 + 3) * 4 + k], acc[3]);
        }
    }
    bf16 o[4];
    #pragma unroll
    for (int j = 0; j < 4; ++j)
        o[j] = __float2bfloat16(__fdividef(acc[j], 1.f + __expf(-acc[j])));
    *(short4*)&xcb[(size_t)bt * DI + d4] = *(short4*)o;
}

// reduce 4 split-K partials -> proj fp32 + projb bf16
__global__ __launch_bounds__(256) void reduce4_kernel(
    const float* __restrict__ parts, float* __restrict__ proj,
    bf16* __restrict__ projb)
{
    int i = blockIdx.x * 256 + threadIdx.x;     // < 393216
    float s = parts[i] + parts[i + 393216] + parts[i + 786432] + parts[i + 1179648];
    proj[i] = s;
    projb[i] = __float2bfloat16(s);
}

// ---------------------------------------------------------------------------
// Selective scan. One thread per (b, d); h[16] in registers; sequential t.
// Recomputes the causal conv inline (3-reg rolling window over xzb). B/C rows
// staged in LDS (broadcast reads). Fuses + xc*D_skip and * silu(z).
// ---------------------------------------------------------------------------
__global__ __launch_bounds__(256) void scan_kernel(
    const float* __restrict__ proj,   // (M_, 96): [64:80)=Bs, [80:96)=Cs
    const float* __restrict__ dtv,    // (M_, DI) softplus dt
    const bf16*  __restrict__ xzb,    // (M_, 4096): [0:2048)=xi, [2048:)=z
    const float* __restrict__ A_log,  // (DI, 16)
    const float* __restrict__ D_skip, // (DI)
    const float* __restrict__ conv_w, // (DI, 4)
    const float* __restrict__ conv_b, // (DI)
    bf16* __restrict__ yb)            // (M_, DI) out
{
    __shared__ float BC[64][32];      // [t][0:16)=B, [16:32)=C
    const int tid = threadIdx.x;
    const int b = blockIdx.y;         // 0..63
    for (int i = tid; i < 64 * 32; i += 256) {
        int t = i >> 5, c = i & 31;
        BC[t][c] = proj[(size_t)(b * 64 + t) * 96 + 64 + c];
    }
    __syncthreads();

    const int d = blockIdx.x * 256 + tid;    // 0..2047
    float A[16];
    #pragma unroll
    for (int n = 0; n < 16; ++n) A[n] = -__expf(A_log[d * 16 + n]);
    const float Dv = D_skip[d];
    const float cw0 = conv_w[d * 4 + 0], cw1 = conv_w[d * 4 + 1];
    const float cw2 = conv_w[d * 4 + 2], cw3 = conv_w[d * 4 + 3];
    const float cb = conv_b[d];
    float h[16];
    #pragma unroll
    for (int n = 0; n < 16; ++n) h[n] = 0.f;
    float w0 = 0.f, w1 = 0.f, w2 = 0.f;      // xzb[t-3], [t-2], [t-1]

    #pragma unroll 2
    for (int t = 0; t < T_; ++t) {
        int row = b * T_ + t;
        size_t off = (size_t)row * DI + d;
        float cur = __bfloat162float(xzb[(size_t)row * 4096 + d]);
        float cacc = cb;
        cacc = fmaf(w0, cw0, cacc); cacc = fmaf(w1, cw1, cacc);
        cacc = fmaf(w2, cw2, cacc); cacc = fmaf(cur, cw3, cacc);
        float xv = __fdividef(cacc, 1.f + __expf(-cacc));   // silu(conv)
        w0 = w1; w1 = w2; w2 = cur;

        float dt = dtv[off];
        float dtx = dt * xv;
        float y = 0.f;
        #pragma unroll
        for (int n = 0; n < 16; ++n) {
            float dA = __expf(dt * A[n]);
            h[n] = fmaf(dA, h[n], dtx * BC[t][n]);
            y = fmaf(h[n], BC[t][16 + n], y);
        }
        float sk = fmaf(xv, Dv, y);
        float z = __bfloat162float(xzb[(size_t)row * 4096 + 2048 + d]);
        float g = __fdividef(z, 1.f + __expf(-z));          // silu(z)
        yb[off] = __float2bfloat16(sk * g);
    }
}

// ---------------------------------------------------------------------------
// Head: out[row, 0:6] = h2[row, :] @ W3 + b3.  One wave per row. h2 is bf16.
// ---------------------------------------------------------------------------
__global__ __launch_bounds__(256) void head_kernel(
    const bf16* __restrict__ h2, const float* __restrict__ W3,
    const float* __restrict__ b3, float* __restrict__ out)
{
    int row = blockIdx.x * 4 + (threadIdx.x >> 6);
    int lane = threadIdx.x & 63;
    const bf16* hr = h2 + (size_t)row * 256;
    float acc[6] = {0.f, 0.f, 0.f, 0.f, 0.f, 0.f};
    #pragma unroll
    for (int kk = 0; kk < 4; ++kk) {
        int k = lane + kk * 64;
        float hv = __bfloat162float(hr[k]);
        #pragma unroll
        for (int n = 0; n < 6; ++n) acc[n] = fmaf(hv, W3[k * 6 + n], acc[n]);
    }
    #pragma unroll
    for (int n = 0; n < 6; ++n) {
        float v = acc[n];
        #pragma unroll
        for (int off = 32; off > 0; off >>= 1) v += __shfl_down(v, off);
        if (lane == 0) out[(size_t)row * 6 + n] = v + b3[n];
    }
}

// ---------------------------------------------------------------------------
extern "C" void kernel_launch(void* const* d_in, const int* in_sizes, int n_in,
                              void* d_out, int out_size, void* d_ws, size_t ws_size,
                              hipStream_t stream)
{
    const float* spatial  = (const float*)d_in[0];
    const float* temporal = (const float*)d_in[1];
    const float* W_in     = (const float*)d_in[2];
    const float* conv_w   = (const float*)d_in[3];
    const float* conv_b   = (const float*)d_in[4];
    const float* W_x      = (const float*)d_in[5];
    const float* W_dt     = (const float*)d_in[6];
    const float* b_dt     = (const float*)d_in[7];
    const float* A_log    = (const float*)d_in[8];
    const float* D_skip   = (const float*)d_in[9];
    const float* W_out    = (const float*)d_in[10];
    const float* W1       = (const float*)d_in[11];
    const float* b1       = (const float*)d_in[12];
    const float* W2       = (const float*)d_in[13];
    const float* b2       = (const float*)d_in[14];
    const float* W3       = (const float*)d_in[15];
    const float* b3       = (const float*)d_in[16];
    float* out = (float*)d_out;

    // Workspace layout (bytes), total 121,765,888.
    char* w = (char*)d_ws;
    bf16*  xzb  = (bf16*)(w);                 // (M_,4096) 32 MiB; dead after scan
    bf16*  f    = (bf16*)(w);                 // (M_,1024) aliases xzb after scan
    bf16*  xcb  = (bf16*)(w + 33554432);      // (M_,2048) 16 MiB; dead after G2
    bf16*  yb   = (bf16*)(w + 33554432);      // (M_,2048) aliases xcb (scan out)
    float* dtv  = (float*)(w + 50331648);     // (M_,2048) fp32 32 MiB
    bf16*  xb   = (bf16*)(w + 83886080);      // (M_,1024) 8 MiB; dead after G1
    bf16*  WinT = (bf16*)(w + 92274688);      // (4096,1024) 8 MiB
    bf16*  WoT  = (bf16*)(w + 100663296);     // (1024,2048) 4 MiB
    bf16*  W1T  = (bf16*)(w + 104857600);     // (512,1024) 1 MiB
    bf16*  W2T  = (bf16*)(w + 105906176);     // (256,512) 256 KiB
    bf16*  WxT  = (bf16*)(w + 106168320);     // (96,2048) 384 KiB
    bf16*  WdT  = (bf16*)(w + 106561536);     // (2048,64) 256 KiB
    float* projp= (float*)(w + 106823680);    // 4x(M_,96) partials 6 MiB
    float* proj = (float*)(w + 113115136);    // (M_,96) fp32 1.5 MiB
    bf16*  projb= (bf16*)(w + 114688000);     // (M_,96) bf16 768 KiB
    bf16*  h1   = (bf16*)(w + 115474432);     // (M_,512) 4 MiB
    bf16*  h2   = (bf16*)(w + 119668736);     // (M_,256) 2 MiB

    dim3 blk(256);

    // 1. concat + all weight transposes
    prep_kernel<<<dim3(11200), blk, 0, stream>>>(
        spatial, temporal, xb, W_in, WinT, W_x, WxT, W_dt, WdT,
        W_out, WoT, W1, W1T, W2, W2T);

    // 2. G1: xzb = xb @ W_in   (4096 x 4096, K=1024)
    gemm_mfma<0, 1, 1, 128, 128><<<dim3(32, 32), blk, 0, stream>>>(
        xb, 1024, WinT, 1024, xzb, 4096, nullptr, 4096, 1024);

    // 3. conv + silu -> xcb (bf16, for G2)
    conv_silu_kernel<<<dim3(8192), blk, 0, stream>>>(xzb, conv_w, conv_b, xcb);

    // 4. G2: proj partials = xc @ W_x   (4096 x 96, K=2048), split-K x4
    gemm_mfma<0, 0, 4, 128, 128><<<dim3(1, 32, 4), blk, 0, stream>>>(
        xcb, 2048, WxT, 2048, projp, 96, nullptr, 96, 2048);

    // 5. reduce partials -> proj (fp32) + projb (bf16)
    reduce4_kernel<<<dim3(1536), blk, 0, stream>>>(projp, proj, projb);

    // 6. G3: dt = softplus(proj[:, :64] @ W_dt + b_dt)   (4096 x 2048, K=64)
    gemm_mfma<2, 0, 1, 128, 64><<<dim3(32, 32), blk, 0, stream>>>(
        projb, 96, WdT, 64, dtv, 2048, b_dt, 2048, 64);

    // 7. Selective scan (inline conv) + skip + gating -> yb
    scan_kernel<<<dim3(8, 64), blk, 0, stream>>>(
        proj, dtv, xzb, A_log, D_skip, conv_w, conv_b, yb);

    // 8. G4: f = y @ W_out   (4096 x 1024, K=2048), 512 blocks
    gemm_mfma<0, 1, 1, 128, 64><<<dim3(16, 32), blk, 0, stream>>>(
        yb, 2048, WoT, 2048, f, 1024, nullptr, 1024, 2048);

    // 9. G5: h1 = relu(f @ W1 + b1)   (4096 x 512, K=1024), 512 blocks
    gemm_mfma<1, 1, 1, 64, 64><<<dim3(8, 64), blk, 0, stream>>>(
        f, 1024, W1T, 1024, h1, 512, b1, 512, 1024);

    // 10. G6: h2 = relu(h1 @ W2 + b2)   (4096 x 256, K=512), 256 blocks
    gemm_mfma<1, 1, 1, 64, 64><<<dim3(4, 64), blk, 0, stream>>>(
        h1, 512, W2T, 512, h2, 256, b2, 256, 512);

    // 11. head
    head_kernel<<<dim3(1024), blk, 0, stream>>>(h2, W3, b3, out);
}

// Round 6
// 390.131 us; speedup vs baseline: 1.1428x; 1.1428x over previous
//
#include <hip/hip_runtime.h>
#include <hip/hip_bf16.h>
#include <math.h>

// Problem constants
#define B_   64
#define T_   64
#define E_   512
#define DM   1024   // d_model
#define DI   2048   // d_inner
#define DS   16     // d_state
#define DTR  64     // dt_rank
#define M_   4096   // B*T rows

typedef __hip_bfloat16 bf16;
typedef __attribute__((ext_vector_type(8))) short bf16x8;   // 8 bf16 = 4 VGPRs
typedef __attribute__((ext_vector_type(4))) float f32x4;

__device__ __forceinline__ float b2f(short s) {
    return __uint_as_float(((unsigned)(unsigned short)s) << 16);
}

// ---------------------------------------------------------------------------
// bf16 MFMA GEMM: C[M x N] = act(A @ B + bias)
//   A  : bf16 (M x K) row-major, lda;  Bt : bf16 (N x K) row-major, ldb
// Block tile BM x BN (BK=32), 256 threads, 2x2 wave grid. BOTH A and B staged
// via global_load_lds width=16 into linear [row][32] LDS — this is the
// best-measured core (R3: G1=64 µs). R4's XOR swizzle (no conflict change,
// +10 µs) and R5's B-direct-from-global (L2 latency on MFMA path, +27 µs)
// are both reverted.
// ACT: 0 none, 1 relu, 2 softplus.
// SPLITK>1: gridDim.z-way K split, writes fp32 partials at z*M_*ldc
// (call with bias=null, ACT=0, OUTBF=0).
// ---------------------------------------------------------------------------
template<int ACT, int OUTBF, int SPLITK, int BM, int BN>
__global__ __launch_bounds__(256) void gemm_mfma(
    const bf16* __restrict__ A, int lda,
    const bf16* __restrict__ Bt, int ldb,
    void* __restrict__ Cv, int ldc,
    const float* __restrict__ bias,
    int Ndim, int Kdim)
{
    __shared__ __align__(16) bf16 As[BM * 32];
    __shared__ __align__(16) bf16 Bs[BN * 32];
    const int tid  = threadIdx.x;
    const int wave = tid >> 6;
    const int lane = tid & 63;
    const int bm = blockIdx.y * BM;
    const int bn = blockIdx.x * BN;
    // staging: per issue, 64 lanes cover 16 rows x 4 k-chunks of 8 bf16 (16 B)
    const int lrow = lane >> 2;               // 0..15
    const int lkc  = (lane & 3) * 8;          // k element offset 0,8,16,24
    constexpr int RPW = (BM + BN) / 4;        // rows staged per wave
    constexpr int NI  = RPW / 16;             // issues per wave
    // compute: 2x2 wave grid
    constexpr int WMT = BM / 32;              // 16-tiles per wave (M)
    constexpr int WNT = BN / 32;              // 16-tiles per wave (N)
    const int wm = (wave >> 1) * (BM / 2);
    const int wn = (wave & 1) * (BN / 2);
    const int fm = lane & 15;                 // fragment row/col
    const int fq = lane >> 4;                 // quad 0..3

    int kstart = 0, kend = Kdim;
    if (SPLITK > 1) {
        int chunk = Kdim / SPLITK;
        kstart = blockIdx.z * chunk;
        kend = kstart + chunk;
    }

    f32x4 acc[WMT][WNT];
    #pragma unroll
    for (int i = 0; i < WMT; ++i)
        #pragma unroll
        for (int j = 0; j < WNT; ++j)
            acc[i][j] = (f32x4){0.f, 0.f, 0.f, 0.f};

    for (int k0 = kstart; k0 < kend; k0 += 32) {
        #pragma unroll
        for (int i = 0; i < NI; ++i) {
            int rowbase = wave * RPW + i * 16;   // wave-uniform
            int row = rowbase + lrow;
            if (rowbase < BM) {
                const bf16* ga = A + (size_t)(bm + row) * lda + k0 + lkc;
                __builtin_amdgcn_global_load_lds(
                    (const __attribute__((address_space(1))) void*)ga,
                    (__attribute__((address_space(3))) void*)&As[rowbase * 32],
                    16, 0, 0);
            } else {
                int brow = bn + row - BM;
                if (brow >= Ndim) brow = Ndim - 1;   // clamp; cols>=Ndim unused
                const bf16* gb = Bt + (size_t)brow * ldb + k0 + lkc;
                __builtin_amdgcn_global_load_lds(
                    (const __attribute__((address_space(1))) void*)gb,
                    (__attribute__((address_space(3))) void*)&Bs[(rowbase - BM) * 32],
                    16, 0, 0);
            }
        }
        __syncthreads();
        bf16x8 a[WMT], b[WNT];
        #pragma unroll
        for (int i = 0; i < WMT; ++i)
            a[i] = *(const bf16x8*)&As[(wm + i * 16 + fm) * 32 + fq * 8];
        #pragma unroll
        for (int j = 0; j < WNT; ++j)
            b[j] = *(const bf16x8*)&Bs[(wn + j * 16 + fm) * 32 + fq * 8];
        #pragma unroll
        for (int i = 0; i < WMT; ++i)
            #pragma unroll
            for (int j = 0; j < WNT; ++j)
                acc[i][j] = __builtin_amdgcn_mfma_f32_16x16x32_bf16(
                    a[i], b[j], acc[i][j], 0, 0, 0);
        __syncthreads();
    }

    // Epilogue. C/D layout: col = lane&15, row = (lane>>4)*4 + r
    size_t zoff = (SPLITK > 1) ? (size_t)blockIdx.z * M_ * ldc : 0;
    #pragma unroll
    for (int i = 0; i < WMT; ++i) {
        int rowb = bm + wm + i * 16 + fq * 4;
        #pragma unroll
        for (int j = 0; j < WNT; ++j) {
            int col = bn + wn + j * 16 + fm;
            if (col < Ndim) {
                float bv = bias ? bias[col] : 0.f;
                #pragma unroll
                for (int r = 0; r < 4; ++r) {
                    float v = acc[i][j][r] + bv;
                    if (ACT == 1) v = fmaxf(v, 0.f);
                    if (ACT == 2) v = (v > 20.f) ? v : __logf(1.f + __expf(v));
                    size_t off = (size_t)(rowb + r) * ldc + col;
                    if (SPLITK > 1) ((float*)Cv)[zoff + off] = v;
                    else if (OUTBF) ((bf16*)Cv)[off] = __float2bfloat16(v);
                    else            ((float*)Cv)[off] = v;
                }
            }
        }
    }
}

// ---------------------------------------------------------------------------
// Split-K partial reduction: out_bf16[i] = act(sum_p parts[p*stride + i] +
// bias[i % NCOL]).  float4-vectorized.  P parts; RELU optional.
// ---------------------------------------------------------------------------
template<int P, int RELU, int NCOL>
__global__ __launch_bounds__(256) void redp_kernel(
    const float* __restrict__ parts, int stride,
    const float* __restrict__ bias, bf16* __restrict__ out)
{
    int i4 = blockIdx.x * 256 + threadIdx.x;     // float4 index
    int i = i4 * 4;
    float4 s = *(const float4*)(parts + i);
    #pragma unroll
    for (int p = 1; p < P; ++p) {
        float4 v = *(const float4*)(parts + (size_t)p * stride + i);
        s.x += v.x; s.y += v.y; s.z += v.z; s.w += v.w;
    }
    if (NCOL > 0) {
        int c = i & (NCOL - 1);
        s.x += bias[c]; s.y += bias[c + 1]; s.z += bias[c + 2]; s.w += bias[c + 3];
    }
    if (RELU) {
        s.x = fmaxf(s.x, 0.f); s.y = fmaxf(s.y, 0.f);
        s.z = fmaxf(s.z, 0.f); s.w = fmaxf(s.w, 0.f);
    }
    bf16 o[4] = {__float2bfloat16(s.x), __float2bfloat16(s.y),
                 __float2bfloat16(s.z), __float2bfloat16(s.w)};
    *(short4*)&out[i] = *(short4*)o;
}

// ---------------------------------------------------------------------------
// prep: one launch doing concat->bf16 (blocks [0,4096)) and all 5 weight
// transposes fp32(K,N) -> bf16(N,K) (32x32 LDS tiles, blocks [4096,11200)).
// ---------------------------------------------------------------------------
__global__ __launch_bounds__(256) void prep_kernel(
    const float* __restrict__ sp, const float* __restrict__ tp,
    bf16* __restrict__ xb,
    const float* __restrict__ W_in,  bf16* __restrict__ WinT,
    const float* __restrict__ W_x,   bf16* __restrict__ WxT,
    const float* __restrict__ W_dt,  bf16* __restrict__ WdT,
    const float* __restrict__ W_out, bf16* __restrict__ WoT,
    const float* __restrict__ W1,    bf16* __restrict__ W1T,
    const float* __restrict__ W2,    bf16* __restrict__ W2T)
{
    __shared__ float tile[32][33];
    const int b = blockIdx.x;
    const int tid = threadIdx.x;
    if (b < 4096) {
        // concat(spatial, temporal) -> xb (M_, 1024)
        int idx = b * 256 + tid;
        int row = idx >> 8;
        int c4 = (idx & 255) * 4;
        const float* src = (c4 < 512) ? (sp + (size_t)row * 512 + c4)
                                      : (tp + (size_t)row * 512 + (c4 - 512));
        float4 v = *(const float4*)src;
        bf16* dst = xb + (size_t)row * 1024 + c4;
        dst[0] = __float2bfloat16(v.x); dst[1] = __float2bfloat16(v.y);
        dst[2] = __float2bfloat16(v.z); dst[3] = __float2bfloat16(v.w);
        return;
    }
    const float* W; bf16* Wt; int K, N, tb;
    if      (b < 8192)  { W = W_in;  Wt = WinT; K = 1024; N = 4096; tb = b - 4096; }
    else if (b < 8384)  { W = W_x;   Wt = WxT;  K = 2048; N = 96;   tb = b - 8192; }
    else if (b < 8512)  { W = W_dt;  Wt = WdT;  K = 64;   N = 2048; tb = b - 8384; }
    else if (b < 10560) { W = W_out; Wt = WoT;  K = 2048; N = 1024; tb = b - 8512; }
    else if (b < 11072) { W = W1;    Wt = W1T;  K = 1024; N = 512;  tb = b - 10560; }
    else                { W = W2;    Wt = W2T;  K = 512;  N = 256;  tb = b - 11072; }
    int nb = N / 32;
    int bn = (tb % nb) * 32, bk = (tb / nb) * 32;
    int tx = tid & 31, ty = tid >> 5;
    #pragma unroll
    for (int i = 0; i < 32; i += 8)
        tile[ty + i][tx] = W[(size_t)(bk + ty + i) * N + bn + tx];
    __syncthreads();
    #pragma unroll
    for (int i = 0; i < 32; i += 8)
        Wt[(size_t)(bn + ty + i) * K + bk + tx] = __float2bfloat16(tile[tx][ty + i]);
}

// ---------------------------------------------------------------------------
// Causal depthwise conv (K=4) + bias + silu, bf16 in, bf16 out (for G2 only;
// the scan recomputes the fp32 conv inline). 4 channels per thread.
// ---------------------------------------------------------------------------
__global__ __launch_bounds__(256) void conv_silu_kernel(
    const bf16* __restrict__ xzb, const float* __restrict__ conv_w,
    const float* __restrict__ conv_b, bf16* __restrict__ xcb)
{
    int idx = blockIdx.x * 256 + threadIdx.x;   // over M_*DI/4
    int d4 = (idx & 511) * 4;                    // DI/4 = 512
    int bt = idx >> 9;
    int t = bt & (T_ - 1);
    float acc[4];
    #pragma unroll
    for (int j = 0; j < 4; ++j) acc[j] = conv_b[d4 + j];
    #pragma unroll
    for (int k = 0; k < 4; ++k) {
        int tt = t + k - 3;
        if (tt >= 0) {
            short4 xv4 = *(const short4*)&xzb[(size_t)(bt + k - 3) * 4096 + d4];
            acc[0] = fmaf(b2f(xv4.x), conv_w[(d4 + 0) * 4 + k], acc[0]);
            acc[1] = fmaf(b2f(xv4.y), conv_w[(d4 + 1) * 4 + k], acc[1]);
            acc[2] = fmaf(b2f(xv4.z), conv_w[(d4 + 2) * 4 + k], acc[2]);
            acc[3] = fmaf(b2f(xv4.w), conv_w[(d4 + 3) * 4 + k], acc[3]);
        }
    }
    bf16 o[4];
    #pragma unroll
    for (int j = 0; j < 4; ++j)
        o[j] = __float2bfloat16(__fdividef(acc[j], 1.f + __expf(-acc[j])));
    *(short4*)&xcb[(size_t)bt * DI + d4] = *(short4*)o;
}

// reduce 4 split-K partials -> proj fp32 + projb bf16
__global__ __launch_bounds__(256) void reduce4_kernel(
    const float* __restrict__ parts, float* __restrict__ proj,
    bf16* __restrict__ projb)
{
    int i = blockIdx.x * 256 + threadIdx.x;     // < 393216
    float s = parts[i] + parts[i + 393216] + parts[i + 786432] + parts[i + 1179648];
    proj[i] = s;
    projb[i] = __float2bfloat16(s);
}

// ---------------------------------------------------------------------------
// Selective scan. One thread per (b, d); h[16] in registers; sequential t.
// Recomputes the causal conv inline (3-reg rolling window over xzb). B/C rows
// staged in LDS (broadcast reads). Fuses + xc*D_skip and * silu(z).
// ---------------------------------------------------------------------------
__global__ __launch_bounds__(256) void scan_kernel(
    const float* __restrict__ proj,   // (M_, 96): [64:80)=Bs, [80:96)=Cs
    const float* __restrict__ dtv,    // (M_, DI) softplus dt
    const bf16*  __restrict__ xzb,    // (M_, 4096): [0:2048)=xi, [2048:)=z
    const float* __restrict__ A_log,  // (DI, 16)
    const float* __restrict__ D_skip, // (DI)
    const float* __restrict__ conv_w, // (DI, 4)
    const float* __restrict__ conv_b, // (DI)
    bf16* __restrict__ yb)            // (M_, DI) out
{
    __shared__ float BC[64][32];      // [t][0:16)=B, [16:32)=C
    const int tid = threadIdx.x;
    const int b = blockIdx.y;         // 0..63
    for (int i = tid; i < 64 * 32; i += 256) {
        int t = i >> 5, c = i & 31;
        BC[t][c] = proj[(size_t)(b * 64 + t) * 96 + 64 + c];
    }
    __syncthreads();

    const int d = blockIdx.x * 256 + tid;    // 0..2047
    float A[16];
    #pragma unroll
    for (int n = 0; n < 16; ++n) A[n] = -__expf(A_log[d * 16 + n]);
    const float Dv = D_skip[d];
    const float cw0 = conv_w[d * 4 + 0], cw1 = conv_w[d * 4 + 1];
    const float cw2 = conv_w[d * 4 + 2], cw3 = conv_w[d * 4 + 3];
    const float cb = conv_b[d];
    float h[16];
    #pragma unroll
    for (int n = 0; n < 16; ++n) h[n] = 0.f;
    float w0 = 0.f, w1 = 0.f, w2 = 0.f;      // xzb[t-3], [t-2], [t-1]

    #pragma unroll 2
    for (int t = 0; t < T_; ++t) {
        int row = b * T_ + t;
        size_t off = (size_t)row * DI + d;
        float cur = __bfloat162float(xzb[(size_t)row * 4096 + d]);
        float cacc = cb;
        cacc = fmaf(w0, cw0, cacc); cacc = fmaf(w1, cw1, cacc);
        cacc = fmaf(w2, cw2, cacc); cacc = fmaf(cur, cw3, cacc);
        float xv = __fdividef(cacc, 1.f + __expf(-cacc));   // silu(conv)
        w0 = w1; w1 = w2; w2 = cur;

        float dt = dtv[off];
        float dtx = dt * xv;
        float y = 0.f;
        #pragma unroll
        for (int n = 0; n < 16; ++n) {
            float dA = __expf(dt * A[n]);
            h[n] = fmaf(dA, h[n], dtx * BC[t][n]);
            y = fmaf(h[n], BC[t][16 + n], y);
        }
        float sk = fmaf(xv, Dv, y);
        float z = __bfloat162float(xzb[(size_t)row * 4096 + 2048 + d]);
        float g = __fdividef(z, 1.f + __expf(-z));          // silu(z)
        yb[off] = __float2bfloat16(sk * g);
    }
}

// ---------------------------------------------------------------------------
// Head: out[row, 0:6] = h2[row, :] @ W3 + b3.  One wave per row. h2 is bf16.
// ---------------------------------------------------------------------------
__global__ __launch_bounds__(256) void head_kernel(
    const bf16* __restrict__ h2, const float* __restrict__ W3,
    const float* __restrict__ b3, float* __restrict__ out)
{
    int row = blockIdx.x * 4 + (threadIdx.x >> 6);
    int lane = threadIdx.x & 63;
    const bf16* hr = h2 + (size_t)row * 256;
    float acc[6] = {0.f, 0.f, 0.f, 0.f, 0.f, 0.f};
    #pragma unroll
    for (int kk = 0; kk < 4; ++kk) {
        int k = lane + kk * 64;
        float hv = __bfloat162float(hr[k]);
        #pragma unroll
        for (int n = 0; n < 6; ++n) acc[n] = fmaf(hv, W3[k * 6 + n], acc[n]);
    }
    #pragma unroll
    for (int n = 0; n < 6; ++n) {
        float v = acc[n];
        #pragma unroll
        for (int off = 32; off > 0; off >>= 1) v += __shfl_down(v, off);
        if (lane == 0) out[(size_t)row * 6 + n] = v + b3[n];
    }
}

// ---------------------------------------------------------------------------
extern "C" void kernel_launch(void* const* d_in, const int* in_sizes, int n_in,
                              void* d_out, int out_size, void* d_ws, size_t ws_size,
                              hipStream_t stream)
{
    const float* spatial  = (const float*)d_in[0];
    const float* temporal = (const float*)d_in[1];
    const float* W_in     = (const float*)d_in[2];
    const float* conv_w   = (const float*)d_in[3];
    const float* conv_b   = (const float*)d_in[4];
    const float* W_x      = (const float*)d_in[5];
    const float* W_dt     = (const float*)d_in[6];
    const float* b_dt     = (const float*)d_in[7];
    const float* A_log    = (const float*)d_in[8];
    const float* D_skip   = (const float*)d_in[9];
    const float* W_out    = (const float*)d_in[10];
    const float* W1       = (const float*)d_in[11];
    const float* b1       = (const float*)d_in[12];
    const float* W2       = (const float*)d_in[13];
    const float* b2       = (const float*)d_in[14];
    const float* W3       = (const float*)d_in[15];
    const float* b3       = (const float*)d_in[16];
    float* out = (float*)d_out;

    // Workspace layout (bytes), total 121,765,888.
    // The 32 MiB region at +50,331,648 is time-shared: dtv (until scan) ->
    // p4 (G4 partials) -> p5 (G5 partials) -> p6 (G6 partials), all ordered
    // by stream sequence.
    char* w = (char*)d_ws;
    bf16*  xzb  = (bf16*)(w);                 // (M_,4096) 32 MiB; dead after scan
    bf16*  f    = (bf16*)(w);                 // (M_,1024) 8 MiB, aliases xzb
    float* dtv  = (float*)(w + 50331648);     // (M_,2048) fp32 32 MiB
    float* p4   = (float*)(w + 50331648);     // 2x(M_,1024) fp32 32 MiB
    float* p5   = (float*)(w + 50331648);     // 4x(M_,512) fp32 32 MiB
    float* p6   = (float*)(w + 50331648);     // 4x(M_,256) fp32 16 MiB
    bf16*  xcb  = (bf16*)(w + 33554432);      // (M_,2048) 16 MiB; dead after G2
    bf16*  yb   = (bf16*)(w + 33554432);      // (M_,2048) aliases xcb (scan out)
    bf16*  xb   = (bf16*)(w + 83886080);      // (M_,1024) 8 MiB; dead after G1
    bf16*  WinT = (bf16*)(w + 92274688);      // (4096,1024) 8 MiB
    bf16*  WoT  = (bf16*)(w + 100663296);     // (1024,2048) 4 MiB
    bf16*  W1T  = (bf16*)(w + 104857600);     // (512,1024) 1 MiB
    bf16*  W2T  = (bf16*)(w + 105906176);     // (256,512) 256 KiB
    bf16*  WxT  = (bf16*)(w + 106168320);     // (96,2048) 384 KiB
    bf16*  WdT  = (bf16*)(w + 106561536);     // (2048,64) 256 KiB
    float* projp= (float*)(w + 106823680);    // 4x(M_,96) partials 6 MiB
    float* proj = (float*)(w + 113115136);    // (M_,96) fp32 1.5 MiB
    bf16*  projb= (bf16*)(w + 114688000);     // (M_,96) bf16 768 KiB
    bf16*  h1   = (bf16*)(w + 115474432);     // (M_,512) 4 MiB
    bf16*  h2   = (bf16*)(w + 119668736);     // (M_,256) 2 MiB

    dim3 blk(256);

    // 1. concat + all weight transposes
    prep_kernel<<<dim3(11200), blk, 0, stream>>>(
        spatial, temporal, xb, W_in, WinT, W_x, WxT, W_dt, WdT,
        W_out, WoT, W1, W1T, W2, W2T);

    // 2. G1: xzb = xb @ W_in   (4096 x 4096, K=1024), 1024 blocks
    gemm_mfma<0, 1, 1, 128, 128><<<dim3(32, 32), blk, 0, stream>>>(
        xb, 1024, WinT, 1024, xzb, 4096, nullptr, 4096, 1024);

    // 3. conv + silu -> xcb (bf16, for G2)
    conv_silu_kernel<<<dim3(8192), blk, 0, stream>>>(xzb, conv_w, conv_b, xcb);

    // 4. G2: proj partials = xc @ W_x   (4096 x 96, K=2048), split-K x4
    gemm_mfma<0, 0, 4, 128, 128><<<dim3(1, 32, 4), blk, 0, stream>>>(
        xcb, 2048, WxT, 2048, projp, 96, nullptr, 96, 2048);

    // 5. reduce partials -> proj (fp32) + projb (bf16)
    reduce4_kernel<<<dim3(1536), blk, 0, stream>>>(projp, proj, projb);

    // 6. G3: dt = softplus(proj[:, :64] @ W_dt + b_dt)  (4096x2048, K=64), 1024 blocks
    gemm_mfma<2, 0, 1, 128, 64><<<dim3(32, 32), blk, 0, stream>>>(
        projb, 96, WdT, 64, dtv, 2048, b_dt, 2048, 64);

    // 7. Selective scan (inline conv) + skip + gating -> yb
    scan_kernel<<<dim3(8, 64), blk, 0, stream>>>(
        proj, dtv, xzb, A_log, D_skip, conv_w, conv_b, yb);

    // 8. G4: p4 = y @ W_out   (4096 x 1024, K=2048), split-K x2 -> 512 blocks
    gemm_mfma<0, 0, 2, 128, 128><<<dim3(8, 32, 2), blk, 0, stream>>>(
        yb, 2048, WoT, 2048, p4, 1024, nullptr, 1024, 2048);

    // 9. f = reduce(p4) -> bf16 (over dead xzb)
    redp_kernel<2, 0, 0><<<dim3(4096), blk, 0, stream>>>(
        p4, 4194304, nullptr, f);

    // 10. G5: p5 = f @ W1   (4096 x 512, K=1024), split-K x4 -> 512 blocks
    gemm_mfma<0, 0, 4, 128, 128><<<dim3(4, 32, 4), blk, 0, stream>>>(
        f, 1024, W1T, 1024, p5, 512, nullptr, 512, 1024);

    // 11. h1 = relu(reduce(p5) + b1) -> bf16
    redp_kernel<4, 1, 512><<<dim3(2048), blk, 0, stream>>>(
        p5, 2097152, b1, h1);

    // 12. G6: p6 = h1 @ W2   (4096 x 256, K=512), split-K x4 -> 256 blocks
    gemm_mfma<0, 0, 4, 128, 128><<<dim3(2, 32, 4), blk, 0, stream>>>(
        h1, 512, W2T, 512, p6, 256, nullptr, 256, 512);

    // 13. h2 = relu(reduce(p6) + b2) -> bf16
    redp_kernel<4, 1, 256><<<dim3(1024), blk, 0, stream>>>(
        p6, 1048576, b2, h2);

    // 14. head
    head_kernel<<<dim3(1024), blk, 0, stream>>>(h2, W3, b3, out);
}

// Round 7
// 349.492 us; speedup vs baseline: 1.2756x; 1.1163x over previous
//
#include <hip/hip_runtime.h>
#include <hip/hip_bf16.h>
#include <math.h>

// Problem constants
#define B_   64
#define T_   64
#define E_   512
#define DM   1024   // d_model
#define DI   2048   // d_inner
#define DS   16     // d_state
#define DTR  64     // dt_rank
#define M_   4096   // B*T rows

typedef __hip_bfloat16 bf16;
typedef __attribute__((ext_vector_type(8))) short bf16x8;   // 8 bf16 = 4 VGPRs
typedef __attribute__((ext_vector_type(4))) float f32x4;

__device__ __forceinline__ float b2f(short s) {
    return __uint_as_float(((unsigned)(unsigned short)s) << 16);
}

// ---------------------------------------------------------------------------
// bf16 MFMA GEMM: C[M x N] = act(A @ B + bias)
//   A  : bf16 (M x K) row-major, lda;  Bt : bf16 (N x K) row-major, ldb
// Block tile BM x BN (BK=32), 256 threads, 2x2 wave grid. BOTH A and B staged
// via global_load_lds width=16 into linear [row][32] LDS — best-measured core
// (R3/R6: G1=64 µs). R4 XOR swizzle and R5 B-direct-from-global both
// regressed and stay reverted.
// ACT: 0 none, 1 relu, 2 softplus.
// SPLITK>1: gridDim.z-way K split, writes fp32 partials at z*M_*ldc
// (call with bias=null, ACT=0, OUTBF=0).
// ---------------------------------------------------------------------------
template<int ACT, int OUTBF, int SPLITK, int BM, int BN>
__global__ __launch_bounds__(256) void gemm_mfma(
    const bf16* __restrict__ A, int lda,
    const bf16* __restrict__ Bt, int ldb,
    void* __restrict__ Cv, int ldc,
    const float* __restrict__ bias,
    int Ndim, int Kdim)
{
    __shared__ __align__(16) bf16 As[BM * 32];
    __shared__ __align__(16) bf16 Bs[BN * 32];
    const int tid  = threadIdx.x;
    const int wave = tid >> 6;
    const int lane = tid & 63;
    const int bm = blockIdx.y * BM;
    const int bn = blockIdx.x * BN;
    // staging: per issue, 64 lanes cover 16 rows x 4 k-chunks of 8 bf16 (16 B)
    const int lrow = lane >> 2;               // 0..15
    const int lkc  = (lane & 3) * 8;          // k element offset 0,8,16,24
    constexpr int RPW = (BM + BN) / 4;        // rows staged per wave
    constexpr int NI  = RPW / 16;             // issues per wave
    // compute: 2x2 wave grid
    constexpr int WMT = BM / 32;              // 16-tiles per wave (M)
    constexpr int WNT = BN / 32;              // 16-tiles per wave (N)
    const int wm = (wave >> 1) * (BM / 2);
    const int wn = (wave & 1) * (BN / 2);
    const int fm = lane & 15;                 // fragment row/col
    const int fq = lane >> 4;                 // quad 0..3

    int kstart = 0, kend = Kdim;
    if (SPLITK > 1) {
        int chunk = Kdim / SPLITK;
        kstart = blockIdx.z * chunk;
        kend = kstart + chunk;
    }

    f32x4 acc[WMT][WNT];
    #pragma unroll
    for (int i = 0; i < WMT; ++i)
        #pragma unroll
        for (int j = 0; j < WNT; ++j)
            acc[i][j] = (f32x4){0.f, 0.f, 0.f, 0.f};

    for (int k0 = kstart; k0 < kend; k0 += 32) {
        #pragma unroll
        for (int i = 0; i < NI; ++i) {
            int rowbase = wave * RPW + i * 16;   // wave-uniform
            int row = rowbase + lrow;
            if (rowbase < BM) {
                const bf16* ga = A + (size_t)(bm + row) * lda + k0 + lkc;
                __builtin_amdgcn_global_load_lds(
                    (const __attribute__((address_space(1))) void*)ga,
                    (__attribute__((address_space(3))) void*)&As[rowbase * 32],
                    16, 0, 0);
            } else {
                int brow = bn + row - BM;
                if (brow >= Ndim) brow = Ndim - 1;   // clamp; cols>=Ndim unused
                const bf16* gb = Bt + (size_t)brow * ldb + k0 + lkc;
                __builtin_amdgcn_global_load_lds(
                    (const __attribute__((address_space(1))) void*)gb,
                    (__attribute__((address_space(3))) void*)&Bs[(rowbase - BM) * 32],
                    16, 0, 0);
            }
        }
        __syncthreads();
        bf16x8 a[WMT], b[WNT];
        #pragma unroll
        for (int i = 0; i < WMT; ++i)
            a[i] = *(const bf16x8*)&As[(wm + i * 16 + fm) * 32 + fq * 8];
        #pragma unroll
        for (int j = 0; j < WNT; ++j)
            b[j] = *(const bf16x8*)&Bs[(wn + j * 16 + fm) * 32 + fq * 8];
        #pragma unroll
        for (int i = 0; i < WMT; ++i)
            #pragma unroll
            for (int j = 0; j < WNT; ++j)
                acc[i][j] = __builtin_amdgcn_mfma_f32_16x16x32_bf16(
                    a[i], b[j], acc[i][j], 0, 0, 0);
        __syncthreads();
    }

    // Epilogue. C/D layout: col = lane&15, row = (lane>>4)*4 + r
    size_t zoff = (SPLITK > 1) ? (size_t)blockIdx.z * M_ * ldc : 0;
    #pragma unroll
    for (int i = 0; i < WMT; ++i) {
        int rowb = bm + wm + i * 16 + fq * 4;
        #pragma unroll
        for (int j = 0; j < WNT; ++j) {
            int col = bn + wn + j * 16 + fm;
            if (col < Ndim) {
                float bv = bias ? bias[col] : 0.f;
                #pragma unroll
                for (int r = 0; r < 4; ++r) {
                    float v = acc[i][j][r] + bv;
                    if (ACT == 1) v = fmaxf(v, 0.f);
                    if (ACT == 2) v = (v > 20.f) ? v : __logf(1.f + __expf(v));
                    size_t off = (size_t)(rowb + r) * ldc + col;
                    if (SPLITK > 1) ((float*)Cv)[zoff + off] = v;
                    else if (OUTBF) ((bf16*)Cv)[off] = __float2bfloat16(v);
                    else            ((float*)Cv)[off] = v;
                }
            }
        }
    }
}

// ---------------------------------------------------------------------------
// Split-K partial reduction: out_bf16[i] = act(sum_p parts[p*stride + i] +
// bias[i % NCOL]).  float4-vectorized.
// ---------------------------------------------------------------------------
template<int P, int RELU, int NCOL>
__global__ __launch_bounds__(256) void redp_kernel(
    const float* __restrict__ parts, int stride,
    const float* __restrict__ bias, bf16* __restrict__ out)
{
    int i4 = blockIdx.x * 256 + threadIdx.x;     // float4 index
    int i = i4 * 4;
    float4 s = *(const float4*)(parts + i);
    #pragma unroll
    for (int p = 1; p < P; ++p) {
        float4 v = *(const float4*)(parts + (size_t)p * stride + i);
        s.x += v.x; s.y += v.y; s.z += v.z; s.w += v.w;
    }
    if (NCOL > 0) {
        int c = i & (NCOL - 1);
        s.x += bias[c]; s.y += bias[c + 1]; s.z += bias[c + 2]; s.w += bias[c + 3];
    }
    if (RELU) {
        s.x = fmaxf(s.x, 0.f); s.y = fmaxf(s.y, 0.f);
        s.z = fmaxf(s.z, 0.f); s.w = fmaxf(s.w, 0.f);
    }
    bf16 o[4] = {__float2bfloat16(s.x), __float2bfloat16(s.y),
                 __float2bfloat16(s.z), __float2bfloat16(s.w)};
    *(short4*)&out[i] = *(short4*)o;
}

// reduce P split-K partials of proj -> proj fp32 + projb bf16
template<int P>
__global__ __launch_bounds__(256) void reduce_proj_kernel(
    const float* __restrict__ parts, float* __restrict__ proj,
    bf16* __restrict__ projb)
{
    int i = blockIdx.x * 256 + threadIdx.x;     // < 393216
    float s = parts[i];
    #pragma unroll
    for (int p = 1; p < P; ++p) s += parts[(size_t)p * 393216 + i];
    proj[i] = s;
    projb[i] = __float2bfloat16(s);
}

// ---------------------------------------------------------------------------
// prep: one launch doing concat->bf16 (blocks [0,4096)) and all 5 weight
// transposes fp32(K,N) -> bf16(N,K) (32x32 LDS tiles, blocks [4096,11200)).
// ---------------------------------------------------------------------------
__global__ __launch_bounds__(256) void prep_kernel(
    const float* __restrict__ sp, const float* __restrict__ tp,
    bf16* __restrict__ xb,
    const float* __restrict__ W_in,  bf16* __restrict__ WinT,
    const float* __restrict__ W_x,   bf16* __restrict__ WxT,
    const float* __restrict__ W_dt,  bf16* __restrict__ WdT,
    const float* __restrict__ W_out, bf16* __restrict__ WoT,
    const float* __restrict__ W1,    bf16* __restrict__ W1T,
    const float* __restrict__ W2,    bf16* __restrict__ W2T)
{
    __shared__ float tile[32][33];
    const int b = blockIdx.x;
    const int tid = threadIdx.x;
    if (b < 4096) {
        // concat(spatial, temporal) -> xb (M_, 1024)
        int idx = b * 256 + tid;
        int row = idx >> 8;
        int c4 = (idx & 255) * 4;
        const float* src = (c4 < 512) ? (sp + (size_t)row * 512 + c4)
                                      : (tp + (size_t)row * 512 + (c4 - 512));
        float4 v = *(const float4*)src;
        bf16* dst = xb + (size_t)row * 1024 + c4;
        dst[0] = __float2bfloat16(v.x); dst[1] = __float2bfloat16(v.y);
        dst[2] = __float2bfloat16(v.z); dst[3] = __float2bfloat16(v.w);
        return;
    }
    const float* W; bf16* Wt; int K, N, tb;
    if      (b < 8192)  { W = W_in;  Wt = WinT; K = 1024; N = 4096; tb = b - 4096; }
    else if (b < 8384)  { W = W_x;   Wt = WxT;  K = 2048; N = 96;   tb = b - 8192; }
    else if (b < 8512)  { W = W_dt;  Wt = WdT;  K = 64;   N = 2048; tb = b - 8384; }
    else if (b < 10560) { W = W_out; Wt = WoT;  K = 2048; N = 1024; tb = b - 8512; }
    else if (b < 11072) { W = W1;    Wt = W1T;  K = 1024; N = 512;  tb = b - 10560; }
    else                { W = W2;    Wt = W2T;  K = 512;  N = 256;  tb = b - 11072; }
    int nb = N / 32;
    int bn = (tb % nb) * 32, bk = (tb / nb) * 32;
    int tx = tid & 31, ty = tid >> 5;
    #pragma unroll
    for (int i = 0; i < 32; i += 8)
        tile[ty + i][tx] = W[(size_t)(bk + ty + i) * N + bn + tx];
    __syncthreads();
    #pragma unroll
    for (int i = 0; i < 32; i += 8)
        Wt[(size_t)(bn + ty + i) * K + bk + tx] = __float2bfloat16(tile[tx][ty + i]);
}

// ---------------------------------------------------------------------------
// Causal depthwise conv (K=4) + bias + silu, bf16 in, bf16 out.
// One CHANNEL per thread (d = idx & 2047): conv_w[d*4..d*4+4) is a single
// coalesced float4 load (16 B lane stride). R6 counters showed the old
// 16-scalar-gather version was TA/L1-serialization bound (66 µs, VALUBusy 9%).
// ---------------------------------------------------------------------------
__global__ __launch_bounds__(256) void conv_silu_kernel(
    const bf16* __restrict__ xzb, const float* __restrict__ conv_w,
    const float* __restrict__ conv_b, bf16* __restrict__ xcb)
{
    int idx = blockIdx.x * 256 + threadIdx.x;   // over M_*DI = 8M
    int d = idx & (DI - 1);
    int bt = idx >> 11;
    int t = bt & (T_ - 1);
    float4 cw = *(const float4*)&conv_w[d * 4];
    float w[4] = {cw.x, cw.y, cw.z, cw.w};
    float acc = conv_b[d];
    #pragma unroll
    for (int k = 0; k < 4; ++k) {
        int tt = t + k - 3;                      // wave-uniform predicate
        if (tt >= 0)
            acc = fmaf(__bfloat162float(xzb[(size_t)(bt + k - 3) * 4096 + d]),
                       w[k], acc);
    }
    xcb[idx] = __float2bfloat16(__fdividef(acc, 1.f + __expf(-acc)));
}

// ---------------------------------------------------------------------------
// Selective scan. One thread per (b, d); h[16] in registers; sequential t.
// Recomputes the causal conv inline (3-reg rolling window over xzb). B/C rows
// staged in LDS (broadcast reads). A_log/conv_w loaded as float4 (coalesced).
// Fuses + xc*D_skip and * silu(z).
// ---------------------------------------------------------------------------
__global__ __launch_bounds__(256) void scan_kernel(
    const float* __restrict__ proj,   // (M_, 96): [64:80)=Bs, [80:96)=Cs
    const float* __restrict__ dtv,    // (M_, DI) softplus dt
    const bf16*  __restrict__ xzb,    // (M_, 4096): [0:2048)=xi, [2048:)=z
    const float* __restrict__ A_log,  // (DI, 16)
    const float* __restrict__ D_skip, // (DI)
    const float* __restrict__ conv_w, // (DI, 4)
    const float* __restrict__ conv_b, // (DI)
    bf16* __restrict__ yb)            // (M_, DI) out
{
    __shared__ float BC[64][32];      // [t][0:16)=B, [16:32)=C
    const int tid = threadIdx.x;
    const int b = blockIdx.y;         // 0..63
    for (int i = tid; i < 64 * 32; i += 256) {
        int t = i >> 5, c = i & 31;
        BC[t][c] = proj[(size_t)(b * 64 + t) * 96 + 64 + c];
    }
    __syncthreads();

    const int d = blockIdx.x * 256 + tid;    // 0..2047
    float av[16];
    const float4* alp = (const float4*)(A_log + d * 16);
    *(float4*)&av[0]  = alp[0];
    *(float4*)&av[4]  = alp[1];
    *(float4*)&av[8]  = alp[2];
    *(float4*)&av[12] = alp[3];
    float A[16];
    #pragma unroll
    for (int n = 0; n < 16; ++n) A[n] = -__expf(av[n]);
    const float Dv = D_skip[d];
    float4 cw = *(const float4*)&conv_w[d * 4];
    const float cb = conv_b[d];
    float h[16];
    #pragma unroll
    for (int n = 0; n < 16; ++n) h[n] = 0.f;
    float w0 = 0.f, w1 = 0.f, w2 = 0.f;      // xzb[t-3], [t-2], [t-1]

    #pragma unroll 2
    for (int t = 0; t < T_; ++t) {
        int row = b * T_ + t;
        size_t off = (size_t)row * DI + d;
        float cur = __bfloat162float(xzb[(size_t)row * 4096 + d]);
        float cacc = cb;
        cacc = fmaf(w0, cw.x, cacc); cacc = fmaf(w1, cw.y, cacc);
        cacc = fmaf(w2, cw.z, cacc); cacc = fmaf(cur, cw.w, cacc);
        float xv = __fdividef(cacc, 1.f + __expf(-cacc));   // silu(conv)
        w0 = w1; w1 = w2; w2 = cur;

        float dt = dtv[off];
        float dtx = dt * xv;
        float y = 0.f;
        #pragma unroll
        for (int n = 0; n < 16; ++n) {
            float dA = __expf(dt * A[n]);
            h[n] = fmaf(dA, h[n], dtx * BC[t][n]);
            y = fmaf(h[n], BC[t][16 + n], y);
        }
        float sk = fmaf(xv, Dv, y);
        float z = __bfloat162float(xzb[(size_t)row * 4096 + 2048 + d]);
        float g = __fdividef(z, 1.f + __expf(-z));          // silu(z)
        yb[off] = __float2bfloat16(sk * g);
    }
}

// ---------------------------------------------------------------------------
// Fused tail: h2 = relu(reduce_P(p6) + b2); out = h2 @ W3 + b3.
// One wave per row; lane covers 4 of 256 cols.
// ---------------------------------------------------------------------------
template<int P>
__global__ __launch_bounds__(256) void head_kernel(
    const float* __restrict__ p6, int stride,
    const float* __restrict__ b2,
    const float* __restrict__ W3, const float* __restrict__ b3,
    float* __restrict__ out)
{
    int row = blockIdx.x * 4 + (threadIdx.x >> 6);
    int lane = threadIdx.x & 63;
    float acc[6] = {0.f, 0.f, 0.f, 0.f, 0.f, 0.f};
    #pragma unroll
    for (int kk = 0; kk < 4; ++kk) {
        int c = lane + kk * 64;
        size_t off = (size_t)row * 256 + c;
        float s = p6[off];
        #pragma unroll
        for (int p = 1; p < P; ++p) s += p6[(size_t)p * stride + off];
        s = fmaxf(s + b2[c], 0.f);
        #pragma unroll
        for (int n = 0; n < 6; ++n) acc[n] = fmaf(s, W3[c * 6 + n], acc[n]);
    }
    #pragma unroll
    for (int n = 0; n < 6; ++n) {
        float v = acc[n];
        #pragma unroll
        for (int off = 32; off > 0; off >>= 1) v += __shfl_down(v, off);
        if (lane == 0) out[(size_t)row * 6 + n] = v + b3[n];
    }
}

// ---------------------------------------------------------------------------
extern "C" void kernel_launch(void* const* d_in, const int* in_sizes, int n_in,
                              void* d_out, int out_size, void* d_ws, size_t ws_size,
                              hipStream_t stream)
{
    const float* spatial  = (const float*)d_in[0];
    const float* temporal = (const float*)d_in[1];
    const float* W_in     = (const float*)d_in[2];
    const float* conv_w   = (const float*)d_in[3];
    const float* conv_b   = (const float*)d_in[4];
    const float* W_x      = (const float*)d_in[5];
    const float* W_dt     = (const float*)d_in[6];
    const float* b_dt     = (const float*)d_in[7];
    const float* A_log    = (const float*)d_in[8];
    const float* D_skip   = (const float*)d_in[9];
    const float* W_out    = (const float*)d_in[10];
    const float* W1       = (const float*)d_in[11];
    const float* b1       = (const float*)d_in[12];
    const float* W2       = (const float*)d_in[13];
    const float* b2       = (const float*)d_in[14];
    const float* W3       = (const float*)d_in[15];
    const float* b3       = (const float*)d_in[16];
    float* out = (float*)d_out;

    // Workspace layout (bytes), total 125,960,192 (< round-1's 135,790,592,
    // known to fit). The 32 MiB region at +50,331,648 is time-shared:
    // dtv (until scan) -> p4 -> p5 -> p6, ordered by stream sequence.
    char* w = (char*)d_ws;
    bf16*  xzb  = (bf16*)(w);                 // (M_,4096) 32 MiB; dead after scan
    bf16*  f    = (bf16*)(w);                 // (M_,1024) 8 MiB, aliases xzb
    float* dtv  = (float*)(w + 50331648);     // (M_,2048) fp32 32 MiB
    float* p4   = (float*)(w + 50331648);     // 2x(M_,1024) fp32 32 MiB
    float* p5   = (float*)(w + 50331648);     // 4x(M_,512) fp32 32 MiB
    float* p6   = (float*)(w + 50331648);     // 4x(M_,256) fp32 16 MiB
    bf16*  xcb  = (bf16*)(w + 33554432);      // (M_,2048) 16 MiB; dead after G2
    bf16*  yb   = (bf16*)(w + 33554432);      // (M_,2048) aliases xcb (scan out)
    bf16*  xb   = (bf16*)(w + 83886080);      // (M_,1024) 8 MiB; dead after G1
    bf16*  WinT = (bf16*)(w + 92274688);      // (4096,1024) 8 MiB
    bf16*  WoT  = (bf16*)(w + 100663296);     // (1024,2048) 4 MiB
    bf16*  W1T  = (bf16*)(w + 104857600);     // (512,1024) 1 MiB
    bf16*  W2T  = (bf16*)(w + 105906176);     // (256,512) 256 KiB
    bf16*  WxT  = (bf16*)(w + 106168320);     // (96,2048) 384 KiB
    bf16*  WdT  = (bf16*)(w + 106561536);     // (2048,64) 256 KiB
    float* projp= (float*)(w + 106823680);    // 8x(M_,96) partials 12 MiB
    float* proj = (float*)(w + 119406592);    // (M_,96) fp32 1.5 MiB
    bf16*  projb= (bf16*)(w + 120979456);     // (M_,96) bf16 768 KiB
    bf16*  h1   = (bf16*)(w + 121765888);     // (M_,512) 4 MiB; end 125960192

    dim3 blk(256);

    // 1. concat + all weight transposes
    prep_kernel<<<dim3(11200), blk, 0, stream>>>(
        spatial, temporal, xb, W_in, WinT, W_x, WxT, W_dt, WdT,
        W_out, WoT, W1, W1T, W2, W2T);

    // 2. G1: xzb = xb @ W_in   (4096 x 4096, K=1024), 1024 blocks
    gemm_mfma<0, 1, 1, 128, 128><<<dim3(32, 32), blk, 0, stream>>>(
        xb, 1024, WinT, 1024, xzb, 4096, nullptr, 4096, 1024);

    // 3. conv + silu -> xcb (bf16, for G2); one channel per thread
    conv_silu_kernel<<<dim3(32768), blk, 0, stream>>>(xzb, conv_w, conv_b, xcb);

    // 4. G2: proj partials = xc @ W_x   (4096 x 96, K=2048), split-K x8
    gemm_mfma<0, 0, 8, 128, 128><<<dim3(1, 32, 8), blk, 0, stream>>>(
        xcb, 2048, WxT, 2048, projp, 96, nullptr, 96, 2048);

    // 5. reduce partials -> proj (fp32) + projb (bf16)
    reduce_proj_kernel<8><<<dim3(1536), blk, 0, stream>>>(projp, proj, projb);

    // 6. G3: dt = softplus(proj[:, :64] @ W_dt + b_dt)  (4096x2048, K=64), 1024 blocks
    gemm_mfma<2, 0, 1, 128, 64><<<dim3(32, 32), blk, 0, stream>>>(
        projb, 96, WdT, 64, dtv, 2048, b_dt, 2048, 64);

    // 7. Selective scan (inline conv) + skip + gating -> yb
    scan_kernel<<<dim3(8, 64), blk, 0, stream>>>(
        proj, dtv, xzb, A_log, D_skip, conv_w, conv_b, yb);

    // 8. G4: p4 = y @ W_out   (4096 x 1024, K=2048), split-K x2 -> 512 blocks
    gemm_mfma<0, 0, 2, 128, 128><<<dim3(8, 32, 2), blk, 0, stream>>>(
        yb, 2048, WoT, 2048, p4, 1024, nullptr, 1024, 2048);

    // 9. f = reduce(p4) -> bf16 (over dead xzb)
    redp_kernel<2, 0, 0><<<dim3(4096), blk, 0, stream>>>(
        p4, 4194304, nullptr, f);

    // 10. G5: p5 = f @ W1   (4096 x 512, K=1024), split-K x4 -> 512 blocks
    gemm_mfma<0, 0, 4, 128, 128><<<dim3(4, 32, 4), blk, 0, stream>>>(
        f, 1024, W1T, 1024, p5, 512, nullptr, 512, 1024);

    // 11. h1 = relu(reduce(p5) + b1) -> bf16
    redp_kernel<4, 1, 512><<<dim3(2048), blk, 0, stream>>>(
        p5, 2097152, b1, h1);

    // 12. G6: p6 = h1 @ W2   (4096 x 256, K=512), split-K x4 -> 256 blocks
    gemm_mfma<0, 0, 4, 128, 128><<<dim3(2, 32, 4), blk, 0, stream>>>(
        h1, 512, W2T, 512, p6, 256, nullptr, 256, 512);

    // 13. fused: out = relu(reduce(p6) + b2) @ W3 + b3
    head_kernel<4><<<dim3(1024), blk, 0, stream>>>(
        p6, 1048576, b2, W3, b3, out);
}

// Round 8
// 321.036 us; speedup vs baseline: 1.3887x; 1.0886x over previous
//
#include <hip/hip_runtime.h>
#include <hip/hip_bf16.h>
#include <math.h>

// Problem constants
#define B_   64
#define T_   64
#define E_   512
#define DM   1024   // d_model
#define DI   2048   // d_inner
#define DS   16     // d_state
#define DTR  64     // dt_rank
#define M_   4096   // B*T rows

typedef __hip_bfloat16 bf16;
typedef __attribute__((ext_vector_type(8))) short bf16x8;   // 8 bf16 = 4 VGPRs
typedef __attribute__((ext_vector_type(4))) float f32x4;

__device__ __forceinline__ float b2f(short s) {
    return __uint_as_float(((unsigned)(unsigned short)s) << 16);
}

// ---------------------------------------------------------------------------
// bf16 MFMA GEMM (generic): C[M x N] = act(A @ B + bias)
// Best-measured core (R3/R6/R7): BK=32, 256 threads, 2x2 wave grid, both
// operands staged via global_load_lds width=16 into linear [row][32] LDS.
// ACT: 0 none, 1 relu, 2 softplus.
// SPLITK>1: gridDim.z-way K split, fp32 partials at z*M_*ldc.
// ---------------------------------------------------------------------------
template<int ACT, int OUTBF, int SPLITK, int BM, int BN>
__global__ __launch_bounds__(256) void gemm_mfma(
    const bf16* __restrict__ A, int lda,
    const bf16* __restrict__ Bt, int ldb,
    void* __restrict__ Cv, int ldc,
    const float* __restrict__ bias,
    int Ndim, int Kdim)
{
    __shared__ __align__(16) bf16 As[BM * 32];
    __shared__ __align__(16) bf16 Bs[BN * 32];
    const int tid  = threadIdx.x;
    const int wave = tid >> 6;
    const int lane = tid & 63;
    const int bm = blockIdx.y * BM;
    const int bn = blockIdx.x * BN;
    const int lrow = lane >> 2;               // 0..15
    const int lkc  = (lane & 3) * 8;          // k element offset 0,8,16,24
    constexpr int RPW = (BM + BN) / 4;        // rows staged per wave
    constexpr int NI  = RPW / 16;             // issues per wave
    constexpr int WMT = BM / 32;
    constexpr int WNT = BN / 32;
    const int wm = (wave >> 1) * (BM / 2);
    const int wn = (wave & 1) * (BN / 2);
    const int fm = lane & 15;
    const int fq = lane >> 4;

    int kstart = 0, kend = Kdim;
    if (SPLITK > 1) {
        int chunk = Kdim / SPLITK;
        kstart = blockIdx.z * chunk;
        kend = kstart + chunk;
    }

    f32x4 acc[WMT][WNT];
    #pragma unroll
    for (int i = 0; i < WMT; ++i)
        #pragma unroll
        for (int j = 0; j < WNT; ++j)
            acc[i][j] = (f32x4){0.f, 0.f, 0.f, 0.f};

    for (int k0 = kstart; k0 < kend; k0 += 32) {
        #pragma unroll
        for (int i = 0; i < NI; ++i) {
            int rowbase = wave * RPW + i * 16;   // wave-uniform
            int row = rowbase + lrow;
            if (rowbase < BM) {
                const bf16* ga = A + (size_t)(bm + row) * lda + k0 + lkc;
                __builtin_amdgcn_global_load_lds(
                    (const __attribute__((address_space(1))) void*)ga,
                    (__attribute__((address_space(3))) void*)&As[rowbase * 32],
                    16, 0, 0);
            } else {
                int brow = bn + row - BM;
                if (brow >= Ndim) brow = Ndim - 1;
                const bf16* gb = Bt + (size_t)brow * ldb + k0 + lkc;
                __builtin_amdgcn_global_load_lds(
                    (const __attribute__((address_space(1))) void*)gb,
                    (__attribute__((address_space(3))) void*)&Bs[(rowbase - BM) * 32],
                    16, 0, 0);
            }
        }
        __syncthreads();
        bf16x8 a[WMT], b[WNT];
        #pragma unroll
        for (int i = 0; i < WMT; ++i)
            a[i] = *(const bf16x8*)&As[(wm + i * 16 + fm) * 32 + fq * 8];
        #pragma unroll
        for (int j = 0; j < WNT; ++j)
            b[j] = *(const bf16x8*)&Bs[(wn + j * 16 + fm) * 32 + fq * 8];
        #pragma unroll
        for (int i = 0; i < WMT; ++i)
            #pragma unroll
            for (int j = 0; j < WNT; ++j)
                acc[i][j] = __builtin_amdgcn_mfma_f32_16x16x32_bf16(
                    a[i], b[j], acc[i][j], 0, 0, 0);
        __syncthreads();
    }

    size_t zoff = (SPLITK > 1) ? (size_t)blockIdx.z * M_ * ldc : 0;
    #pragma unroll
    for (int i = 0; i < WMT; ++i) {
        int rowb = bm + wm + i * 16 + fq * 4;
        #pragma unroll
        for (int j = 0; j < WNT; ++j) {
            int col = bn + wn + j * 16 + fm;
            if (col < Ndim) {
                float bv = bias ? bias[col] : 0.f;
                #pragma unroll
                for (int r = 0; r < 4; ++r) {
                    float v = acc[i][j][r] + bv;
                    if (ACT == 1) v = fmaxf(v, 0.f);
                    if (ACT == 2) v = (v > 20.f) ? v : __logf(1.f + __expf(v));
                    size_t off = (size_t)(rowb + r) * ldc + col;
                    if (SPLITK > 1) ((float*)Cv)[zoff + off] = v;
                    else if (OUTBF) ((bf16*)Cv)[off] = __float2bfloat16(v);
                    else            ((float*)Cv)[off] = v;
                }
            }
        }
    }
}

// ---------------------------------------------------------------------------
// G1 specialized: xz = xb @ W_in (4096x4096, K=1024) with the conv+silu FUSED
// into the epilogue. A 128-row tile holds exactly 2 complete sequences
// (T=64 | 128), so the causal depthwise conv is tile-local:
//   cols <  2048 (xi): acc tile -> LDS (stride 136, b128-aligned), per-
//     (seq,col) thread runs the 64-step rolling conv+silu IN-PLACE, then
//     coalesced bf16x8 stores -> xcb. xi itself is never written to HBM.
//   cols >= 2048 (z):  plain bf16 write -> zb.
// K-loop is byte-identical to the proven gemm_mfma core. LDS: As/Bs (16 KB)
// alias the front of the 34816 B conv buffer (dead after the K-loop's final
// barrier, which also drains the async staging writes).
// ---------------------------------------------------------------------------
__global__ __launch_bounds__(256) void gemm_g1_conv(
    const bf16* __restrict__ A,      // xb (M_,1024)
    const bf16* __restrict__ Bt,     // WinT (4096,1024)
    bf16* __restrict__ xcb,          // (M_,2048) silu(conv(xi))
    bf16* __restrict__ zb,           // (M_,2048) z
    const float* __restrict__ conv_w,
    const float* __restrict__ conv_b)
{
    constexpr int XS = 136;                       // padded X stride (elems)
    __shared__ __align__(16) bf16 smem[128 * XS]; // 34816 B
    const int tid  = threadIdx.x;
    const int wave = tid >> 6;
    const int lane = tid & 63;
    const int bm = blockIdx.y * 128;
    const int bn = blockIdx.x * 128;
    const int lrow = lane >> 2;
    const int lkc  = (lane & 3) * 8;
    const int wm = (wave >> 1) * 64;
    const int wn = (wave & 1) * 64;
    const int fm = lane & 15;
    const int fq = lane >> 4;

    f32x4 acc[4][4];
    #pragma unroll
    for (int i = 0; i < 4; ++i)
        #pragma unroll
        for (int j = 0; j < 4; ++j)
            acc[i][j] = (f32x4){0.f, 0.f, 0.f, 0.f};

    for (int k0 = 0; k0 < 1024; k0 += 32) {
        #pragma unroll
        for (int i = 0; i < 4; ++i) {
            int rowbase = wave * 64 + i * 16;     // wave-uniform
            int row = rowbase + lrow;
            if (rowbase < 128) {
                const bf16* ga = A + (size_t)(bm + row) * 1024 + k0 + lkc;
                __builtin_amdgcn_global_load_lds(
                    (const __attribute__((address_space(1))) void*)ga,
                    (__attribute__((address_space(3))) void*)&smem[rowbase * 32],
                    16, 0, 0);
            } else {
                const bf16* gb = Bt + (size_t)(bn + row - 128) * 1024 + k0 + lkc;
                __builtin_amdgcn_global_load_lds(
                    (const __attribute__((address_space(1))) void*)gb,
                    (__attribute__((address_space(3))) void*)&smem[4096 + (rowbase - 128) * 32],
                    16, 0, 0);
            }
        }
        __syncthreads();
        bf16x8 a[4], b[4];
        #pragma unroll
        for (int i = 0; i < 4; ++i)
            a[i] = *(const bf16x8*)&smem[(wm + i * 16 + fm) * 32 + fq * 8];
        #pragma unroll
        for (int j = 0; j < 4; ++j)
            b[j] = *(const bf16x8*)&smem[4096 + (wn + j * 16 + fm) * 32 + fq * 8];
        #pragma unroll
        for (int i = 0; i < 4; ++i)
            #pragma unroll
            for (int j = 0; j < 4; ++j)
                acc[i][j] = __builtin_amdgcn_mfma_f32_16x16x32_bf16(
                    a[i], b[j], acc[i][j], 0, 0, 0);
        __syncthreads();   // also makes As/Bs region dead -> reusable as X
    }

    if (bn < 2048) {
        // ---- xi half: acc -> X[row][col] (bf16)
        #pragma unroll
        for (int i = 0; i < 4; ++i) {
            int rowb = wm + i * 16 + fq * 4;
            #pragma unroll
            for (int j = 0; j < 4; ++j) {
                int col = wn + j * 16 + fm;
                #pragma unroll
                for (int r = 0; r < 4; ++r)
                    smem[(rowb + r) * XS + col] = __float2bfloat16(acc[i][j][r]);
            }
        }
        __syncthreads();
        // ---- rolling causal conv + silu, in-place along t
        {
            int col = tid & 127;
            int seq = tid >> 7;                   // 0 or 1
            int gcol = bn + col;
            float4 cw = *(const float4*)&conv_w[gcol * 4];
            float cb = conv_b[gcol];
            float w0 = 0.f, w1 = 0.f, w2 = 0.f;
            int base = seq * 64;
            for (int t = 0; t < 64; ++t) {
                int idx = (base + t) * XS + col;
                float cur = __bfloat162float(smem[idx]);
                float cacc = cb;
                cacc = fmaf(w0, cw.x, cacc); cacc = fmaf(w1, cw.y, cacc);
                cacc = fmaf(w2, cw.z, cacc); cacc = fmaf(cur, cw.w, cacc);
                smem[idx] = __float2bfloat16(__fdividef(cacc, 1.f + __expf(-cacc)));
                w0 = w1; w1 = w2; w2 = cur;
            }
        }
        __syncthreads();
        // ---- coalesced bf16x8 store -> xcb
        #pragma unroll
        for (int it = 0; it < 8; ++it) {
            int g = it * 256 + tid;               // 2048 groups of 8
            int row = g >> 4;
            int cg = (g & 15) * 8;
            bf16x8 v = *(const bf16x8*)&smem[row * XS + cg];
            *(bf16x8*)&xcb[(size_t)(bm + row) * 2048 + bn + cg] = v;
        }
    } else {
        // ---- z half: plain bf16 write
        #pragma unroll
        for (int i = 0; i < 4; ++i) {
            int rowb = bm + wm + i * 16 + fq * 4;
            #pragma unroll
            for (int j = 0; j < 4; ++j) {
                int col = bn - 2048 + wn + j * 16 + fm;
                #pragma unroll
                for (int r = 0; r < 4; ++r)
                    zb[(size_t)(rowb + r) * 2048 + col] =
                        __float2bfloat16(acc[i][j][r]);
            }
        }
    }
}

// ---------------------------------------------------------------------------
// Split-K partial reduction: out_bf16 = act(sum_p parts + bias)
// ---------------------------------------------------------------------------
template<int P, int RELU, int NCOL>
__global__ __launch_bounds__(256) void redp_kernel(
    const float* __restrict__ parts, int stride,
    const float* __restrict__ bias, bf16* __restrict__ out)
{
    int i4 = blockIdx.x * 256 + threadIdx.x;
    int i = i4 * 4;
    float4 s = *(const float4*)(parts + i);
    #pragma unroll
    for (int p = 1; p < P; ++p) {
        float4 v = *(const float4*)(parts + (size_t)p * stride + i);
        s.x += v.x; s.y += v.y; s.z += v.z; s.w += v.w;
    }
    if (NCOL > 0) {
        int c = i & (NCOL - 1);
        s.x += bias[c]; s.y += bias[c + 1]; s.z += bias[c + 2]; s.w += bias[c + 3];
    }
    if (RELU) {
        s.x = fmaxf(s.x, 0.f); s.y = fmaxf(s.y, 0.f);
        s.z = fmaxf(s.z, 0.f); s.w = fmaxf(s.w, 0.f);
    }
    bf16 o[4] = {__float2bfloat16(s.x), __float2bfloat16(s.y),
                 __float2bfloat16(s.z), __float2bfloat16(s.w)};
    *(short4*)&out[i] = *(short4*)o;
}

// reduce P split-K partials of proj -> proj fp32 + projb bf16
template<int P>
__global__ __launch_bounds__(256) void reduce_proj_kernel(
    const float* __restrict__ parts, float* __restrict__ proj,
    bf16* __restrict__ projb)
{
    int i = blockIdx.x * 256 + threadIdx.x;     // < 393216
    float s = parts[i];
    #pragma unroll
    for (int p = 1; p < P; ++p) s += parts[(size_t)p * 393216 + i];
    proj[i] = s;
    projb[i] = __float2bfloat16(s);
}

// ---------------------------------------------------------------------------
// prep: concat->bf16 (blocks [0,4096)) + all 5 weight transposes
// fp32(K,N) -> bf16(N,K) (32x32 LDS tiles, blocks [4096,11200)).
// ---------------------------------------------------------------------------
__global__ __launch_bounds__(256) void prep_kernel(
    const float* __restrict__ sp, const float* __restrict__ tp,
    bf16* __restrict__ xb,
    const float* __restrict__ W_in,  bf16* __restrict__ WinT,
    const float* __restrict__ W_x,   bf16* __restrict__ WxT,
    const float* __restrict__ W_dt,  bf16* __restrict__ WdT,
    const float* __restrict__ W_out, bf16* __restrict__ WoT,
    const float* __restrict__ W1,    bf16* __restrict__ W1T,
    const float* __restrict__ W2,    bf16* __restrict__ W2T)
{
    __shared__ float tile[32][33];
    const int b = blockIdx.x;
    const int tid = threadIdx.x;
    if (b < 4096) {
        int idx = b * 256 + tid;
        int row = idx >> 8;
        int c4 = (idx & 255) * 4;
        const float* src = (c4 < 512) ? (sp + (size_t)row * 512 + c4)
                                      : (tp + (size_t)row * 512 + (c4 - 512));
        float4 v = *(const float4*)src;
        bf16* dst = xb + (size_t)row * 1024 + c4;
        dst[0] = __float2bfloat16(v.x); dst[1] = __float2bfloat16(v.y);
        dst[2] = __float2bfloat16(v.z); dst[3] = __float2bfloat16(v.w);
        return;
    }
    const float* W; bf16* Wt; int K, N, tb;
    if      (b < 8192)  { W = W_in;  Wt = WinT; K = 1024; N = 4096; tb = b - 4096; }
    else if (b < 8384)  { W = W_x;   Wt = WxT;  K = 2048; N = 96;   tb = b - 8192; }
    else if (b < 8512)  { W = W_dt;  Wt = WdT;  K = 64;   N = 2048; tb = b - 8384; }
    else if (b < 10560) { W = W_out; Wt = WoT;  K = 2048; N = 1024; tb = b - 8512; }
    else if (b < 11072) { W = W1;    Wt = W1T;  K = 1024; N = 512;  tb = b - 10560; }
    else                { W = W2;    Wt = W2T;  K = 512;  N = 256;  tb = b - 11072; }
    int nb = N / 32;
    int bn = (tb % nb) * 32, bk = (tb / nb) * 32;
    int tx = tid & 31, ty = tid >> 5;
    #pragma unroll
    for (int i = 0; i < 32; i += 8)
        tile[ty + i][tx] = W[(size_t)(bk + ty + i) * N + bn + tx];
    __syncthreads();
    #pragma unroll
    for (int i = 0; i < 32; i += 8)
        Wt[(size_t)(bn + ty + i) * K + bk + tx] = __float2bfloat16(tile[tx][ty + i]);
}

// ---------------------------------------------------------------------------
// Selective scan. One thread per (b, d); h[16] in registers; sequential t.
// Reads xc (bf16, from G1's fused epilogue), dt (bf16), z (bf16). Writes the
// gated y IN-PLACE over xcy (per-element read-then-write, race-free).
// B/C rows staged in LDS (broadcast reads). A_log loaded as float4.
// ---------------------------------------------------------------------------
__global__ __launch_bounds__(256) void scan_kernel(
    const float* __restrict__ proj,   // (M_, 96): [64:80)=Bs, [80:96)=Cs
    const bf16*  __restrict__ dtb,    // (M_, DI) softplus dt (bf16)
    bf16* __restrict__ xcy,           // (M_, DI) in: xc, out: gated y
    const bf16*  __restrict__ zb,     // (M_, DI) z
    const float* __restrict__ A_log,  // (DI, 16)
    const float* __restrict__ D_skip) // (DI)
{
    __shared__ float BC[64][32];      // [t][0:16)=B, [16:32)=C
    const int tid = threadIdx.x;
    const int b = blockIdx.y;         // 0..63
    for (int i = tid; i < 64 * 32; i += 256) {
        int t = i >> 5, c = i & 31;
        BC[t][c] = proj[(size_t)(b * 64 + t) * 96 + 64 + c];
    }
    __syncthreads();

    const int d = blockIdx.x * 256 + tid;    // 0..2047
    float av[16];
    const float4* alp = (const float4*)(A_log + d * 16);
    *(float4*)&av[0]  = alp[0];
    *(float4*)&av[4]  = alp[1];
    *(float4*)&av[8]  = alp[2];
    *(float4*)&av[12] = alp[3];
    float A[16];
    #pragma unroll
    for (int n = 0; n < 16; ++n) A[n] = -__expf(av[n]);
    const float Dv = D_skip[d];
    float h[16];
    #pragma unroll
    for (int n = 0; n < 16; ++n) h[n] = 0.f;

    #pragma unroll 2
    for (int t = 0; t < T_; ++t) {
        int row = b * T_ + t;
        size_t off = (size_t)row * DI + d;
        float xv = __bfloat162float(xcy[off]);
        float dt = __bfloat162float(dtb[off]);
        float dtx = dt * xv;
        float y = 0.f;
        #pragma unroll
        for (int n = 0; n < 16; ++n) {
            float dA = __expf(dt * A[n]);
            h[n] = fmaf(dA, h[n], dtx * BC[t][n]);
            y = fmaf(h[n], BC[t][16 + n], y);
        }
        float sk = fmaf(xv, Dv, y);
        float z = __bfloat162float(zb[off]);
        float g = __fdividef(z, 1.f + __expf(-z));          // silu(z)
        xcy[off] = __float2bfloat16(sk * g);
    }
}

// ---------------------------------------------------------------------------
// Fused tail: h2 = relu(reduce_P(p6) + b2); out = h2 @ W3 + b3.
// ---------------------------------------------------------------------------
template<int P>
__global__ __launch_bounds__(256) void head_kernel(
    const float* __restrict__ p6, int stride,
    const float* __restrict__ b2,
    const float* __restrict__ W3, const float* __restrict__ b3,
    float* __restrict__ out)
{
    int row = blockIdx.x * 4 + (threadIdx.x >> 6);
    int lane = threadIdx.x & 63;
    float acc[6] = {0.f, 0.f, 0.f, 0.f, 0.f, 0.f};
    #pragma unroll
    for (int kk = 0; kk < 4; ++kk) {
        int c = lane + kk * 64;
        size_t off = (size_t)row * 256 + c;
        float s = p6[off];
        #pragma unroll
        for (int p = 1; p < P; ++p) s += p6[(size_t)p * stride + off];
        s = fmaxf(s + b2[c], 0.f);
        #pragma unroll
        for (int n = 0; n < 6; ++n) acc[n] = fmaf(s, W3[c * 6 + n], acc[n]);
    }
    #pragma unroll
    for (int n = 0; n < 6; ++n) {
        float v = acc[n];
        #pragma unroll
        for (int off = 32; off > 0; off >>= 1) v += __shfl_down(v, off);
        if (lane == 0) out[(size_t)row * 6 + n] = v + b3[n];
    }
}

// ---------------------------------------------------------------------------
extern "C" void kernel_launch(void* const* d_in, const int* in_sizes, int n_in,
                              void* d_out, int out_size, void* d_ws, size_t ws_size,
                              hipStream_t stream)
{
    const float* spatial  = (const float*)d_in[0];
    const float* temporal = (const float*)d_in[1];
    const float* W_in     = (const float*)d_in[2];
    const float* conv_w   = (const float*)d_in[3];
    const float* conv_b   = (const float*)d_in[4];
    const float* W_x      = (const float*)d_in[5];
    const float* W_dt     = (const float*)d_in[6];
    const float* b_dt     = (const float*)d_in[7];
    const float* A_log    = (const float*)d_in[8];
    const float* D_skip   = (const float*)d_in[9];
    const float* W_out    = (const float*)d_in[10];
    const float* W1       = (const float*)d_in[11];
    const float* b1       = (const float*)d_in[12];
    const float* W2       = (const float*)d_in[13];
    const float* b2       = (const float*)d_in[14];
    const float* W3       = (const float*)d_in[15];
    const float* b3       = (const float*)d_in[16];
    float* out = (float*)d_out;

    // Workspace layout (bytes), total 109,182,976.
    // +0        : xcb (M_,2048 bf16, 16 MiB) = scan's in-place y = G4's A.
    //             After G4, redp4 overwrites the front 8 MiB with f.
    // +33554432 : 32 MiB time-shared: dtb (bf16 16 MiB, until scan) ->
    //             p4 (2x16 MiB) -> p5 (4x8 MiB) -> p6 (4x4 MiB).
    char* w = (char*)d_ws;
    bf16*  xcb  = (bf16*)(w);                 // (M_,2048) xc -> y (in-place)
    bf16*  f    = (bf16*)(w);                 // (M_,1024) 8 MiB, after G4
    bf16*  zb   = (bf16*)(w + 16777216);      // (M_,2048) 16 MiB
    bf16*  dtb  = (bf16*)(w + 33554432);      // (M_,2048) bf16
    float* p4   = (float*)(w + 33554432);     // 2x(M_,1024) fp32
    float* p5   = (float*)(w + 33554432);     // 4x(M_,512) fp32
    float* p6   = (float*)(w + 33554432);     // 4x(M_,256) fp32
    bf16*  xb   = (bf16*)(w + 67108864);      // (M_,1024) 8 MiB
    bf16*  WinT = (bf16*)(w + 75497472);      // (4096,1024) 8 MiB
    bf16*  WoT  = (bf16*)(w + 83886080);      // (1024,2048) 4 MiB
    bf16*  W1T  = (bf16*)(w + 88080384);      // (512,1024) 1 MiB
    bf16*  W2T  = (bf16*)(w + 89128960);      // (256,512) 256 KiB
    bf16*  WxT  = (bf16*)(w + 89391104);      // (96,2048) 384 KiB
    bf16*  WdT  = (bf16*)(w + 89784320);      // (2048,64) 256 KiB
    float* projp= (float*)(w + 90046464);     // 8x(M_,96) partials 12 MiB
    float* proj = (float*)(w + 102629376);    // (M_,96) fp32 1.5 MiB
    bf16*  projb= (bf16*)(w + 104202240);     // (M_,96) bf16 768 KiB
    bf16*  h1   = (bf16*)(w + 104988672);     // (M_,512) 4 MiB; end 109182976

    dim3 blk(256);

    // 1. concat + all weight transposes
    prep_kernel<<<dim3(11200), blk, 0, stream>>>(
        spatial, temporal, xb, W_in, WinT, W_x, WxT, W_dt, WdT,
        W_out, WoT, W1, W1T, W2, W2T);

    // 2. G1 (+fused conv/silu): xcb = silu(conv(xb @ W_in[:, :2048])),
    //    zb = xb @ W_in[:, 2048:]
    gemm_g1_conv<<<dim3(32, 32), blk, 0, stream>>>(
        xb, WinT, xcb, zb, conv_w, conv_b);

    // 3. G2: proj partials = xc @ W_x   (4096 x 96, K=2048), split-K x8
    gemm_mfma<0, 0, 8, 128, 128><<<dim3(1, 32, 8), blk, 0, stream>>>(
        xcb, 2048, WxT, 2048, projp, 96, nullptr, 96, 2048);

    // 4. reduce partials -> proj (fp32) + projb (bf16)
    reduce_proj_kernel<8><<<dim3(1536), blk, 0, stream>>>(projp, proj, projb);

    // 5. G3: dt = softplus(proj[:, :64] @ W_dt + b_dt) -> bf16 dtb
    gemm_mfma<2, 1, 1, 128, 64><<<dim3(32, 32), blk, 0, stream>>>(
        projb, 96, WdT, 64, dtb, 2048, b_dt, 2048, 64);

    // 6. Selective scan + skip + gating, y in-place over xcb
    scan_kernel<<<dim3(8, 64), blk, 0, stream>>>(
        proj, dtb, xcb, zb, A_log, D_skip);

    // 7. G4: p4 = y @ W_out   (4096 x 1024, K=2048), split-K x2 -> 512 blocks
    gemm_mfma<0, 0, 2, 128, 128><<<dim3(8, 32, 2), blk, 0, stream>>>(
        xcb, 2048, WoT, 2048, p4, 1024, nullptr, 1024, 2048);

    // 8. f = reduce(p4) -> bf16 (over dead xcb front)
    redp_kernel<2, 0, 0><<<dim3(4096), blk, 0, stream>>>(
        p4, 4194304, nullptr, f);

    // 9. G5: p5 = f @ W1   (4096 x 512, K=1024), split-K x4 -> 512 blocks
    gemm_mfma<0, 0, 4, 128, 128><<<dim3(4, 32, 4), blk, 0, stream>>>(
        f, 1024, W1T, 1024, p5, 512, nullptr, 512, 1024);

    // 10. h1 = relu(reduce(p5) + b1) -> bf16
    redp_kernel<4, 1, 512><<<dim3(2048), blk, 0, stream>>>(
        p5, 2097152, b1, h1);

    // 11. G6: p6 = h1 @ W2   (4096 x 256, K=512), split-K x4 -> 256 blocks
    gemm_mfma<0, 0, 4, 128, 128><<<dim3(2, 32, 4), blk, 0, stream>>>(
        h1, 512, W2T, 512, p6, 256, nullptr, 256, 512);

    // 12. fused: out = relu(reduce(p6) + b2) @ W3 + b3
    head_kernel<4><<<dim3(1024), blk, 0, stream>>>(
        p6, 1048576, b2, W3, b3, out);
}

// Round 9
// 304.137 us; speedup vs baseline: 1.4659x; 1.0556x over previous
//
#include <hip/hip_runtime.h>
#include <hip/hip_bf16.h>
#include <math.h>

// Problem constants
#define B_   64
#define T_   64
#define E_   512
#define DM   1024   // d_model
#define DI   2048   // d_inner
#define DS   16     // d_state
#define DTR  64     // dt_rank
#define M_   4096   // B*T rows

typedef __hip_bfloat16 bf16;
typedef __attribute__((ext_vector_type(8))) short bf16x8;   // 8 bf16 = 4 VGPRs
typedef __attribute__((ext_vector_type(4))) float f32x4;

__device__ __forceinline__ float b2f(short s) {
    return __uint_as_float(((unsigned)(unsigned short)s) << 16);
}

// ---------------------------------------------------------------------------
// bf16 MFMA GEMM (generic): C[M x N] = act(A @ B + bias)
// Best-measured core (R3..R8): BK=32, 256 threads, 2x2 wave grid, both
// operands staged via global_load_lds width=16 into linear [row][32] LDS.
// ACT: 0 none, 1 relu, 2 softplus.
// SPLITK>1: gridDim.z-way K split, fp32 partials at z*Mdim*ldc (Mdim = M_
// for activation GEMMs; pass bias=null, ACT=0, OUTBF=0).
// ---------------------------------------------------------------------------
template<int ACT, int OUTBF, int SPLITK, int BM, int BN>
__global__ __launch_bounds__(256) void gemm_mfma(
    const bf16* __restrict__ A, int lda,
    const bf16* __restrict__ Bt, int ldb,
    void* __restrict__ Cv, int ldc,
    const float* __restrict__ bias,
    int Ndim, int Kdim)
{
    __shared__ __align__(16) bf16 As[BM * 32];
    __shared__ __align__(16) bf16 Bs[BN * 32];
    const int tid  = threadIdx.x;
    const int wave = tid >> 6;
    const int lane = tid & 63;
    const int bm = blockIdx.y * BM;
    const int bn = blockIdx.x * BN;
    const int lrow = lane >> 2;               // 0..15
    const int lkc  = (lane & 3) * 8;          // k element offset 0,8,16,24
    constexpr int RPW = (BM + BN) / 4;        // rows staged per wave
    constexpr int NI  = RPW / 16;             // issues per wave
    constexpr int WMT = BM / 32;
    constexpr int WNT = BN / 32;
    const int wm = (wave >> 1) * (BM / 2);
    const int wn = (wave & 1) * (BN / 2);
    const int fm = lane & 15;
    const int fq = lane >> 4;

    int kstart = 0, kend = Kdim;
    if (SPLITK > 1) {
        int chunk = Kdim / SPLITK;
        kstart = blockIdx.z * chunk;
        kend = kstart + chunk;
    }

    f32x4 acc[WMT][WNT];
    #pragma unroll
    for (int i = 0; i < WMT; ++i)
        #pragma unroll
        for (int j = 0; j < WNT; ++j)
            acc[i][j] = (f32x4){0.f, 0.f, 0.f, 0.f};

    for (int k0 = kstart; k0 < kend; k0 += 32) {
        #pragma unroll
        for (int i = 0; i < NI; ++i) {
            int rowbase = wave * RPW + i * 16;   // wave-uniform
            int row = rowbase + lrow;
            if (rowbase < BM) {
                const bf16* ga = A + (size_t)(bm + row) * lda + k0 + lkc;
                __builtin_amdgcn_global_load_lds(
                    (const __attribute__((address_space(1))) void*)ga,
                    (__attribute__((address_space(3))) void*)&As[rowbase * 32],
                    16, 0, 0);
            } else {
                int brow = bn + row - BM;
                if (brow >= Ndim) brow = Ndim - 1;
                const bf16* gb = Bt + (size_t)brow * ldb + k0 + lkc;
                __builtin_amdgcn_global_load_lds(
                    (const __attribute__((address_space(1))) void*)gb,
                    (__attribute__((address_space(3))) void*)&Bs[(rowbase - BM) * 32],
                    16, 0, 0);
            }
        }
        __syncthreads();
        bf16x8 a[WMT], b[WNT];
        #pragma unroll
        for (int i = 0; i < WMT; ++i)
            a[i] = *(const bf16x8*)&As[(wm + i * 16 + fm) * 32 + fq * 8];
        #pragma unroll
        for (int j = 0; j < WNT; ++j)
            b[j] = *(const bf16x8*)&Bs[(wn + j * 16 + fm) * 32 + fq * 8];
        #pragma unroll
        for (int i = 0; i < WMT; ++i)
            #pragma unroll
            for (int j = 0; j < WNT; ++j)
                acc[i][j] = __builtin_amdgcn_mfma_f32_16x16x32_bf16(
                    a[i], b[j], acc[i][j], 0, 0, 0);
        __syncthreads();
    }

    size_t zoff = (SPLITK > 1) ? (size_t)blockIdx.z * M_ * ldc : 0;
    #pragma unroll
    for (int i = 0; i < WMT; ++i) {
        int rowb = bm + wm + i * 16 + fq * 4;
        #pragma unroll
        for (int j = 0; j < WNT; ++j) {
            int col = bn + wn + j * 16 + fm;
            if (col < Ndim) {
                float bv = bias ? bias[col] : 0.f;
                #pragma unroll
                for (int r = 0; r < 4; ++r) {
                    float v = acc[i][j][r] + bv;
                    if (ACT == 1) v = fmaxf(v, 0.f);
                    if (ACT == 2) v = (v > 20.f) ? v : __logf(1.f + __expf(v));
                    size_t off = (size_t)(rowb + r) * ldc + col;
                    if (SPLITK > 1) ((float*)Cv)[zoff + off] = v;
                    else if (OUTBF) ((bf16*)Cv)[off] = __float2bfloat16(v);
                    else            ((float*)Cv)[off] = v;
                }
            }
        }
    }
}

// ---------------------------------------------------------------------------
// G1 specialized: xz = xb @ W_in with conv+silu fused into the epilogue
// (R8 — measured free: 64 µs, same as unfused G1).
// ---------------------------------------------------------------------------
__global__ __launch_bounds__(256) void gemm_g1_conv(
    const bf16* __restrict__ A,      // xb (M_,1024)
    const bf16* __restrict__ Bt,     // WinT (4096,1024)
    bf16* __restrict__ xcb,          // (M_,2048) silu(conv(xi))
    bf16* __restrict__ zb,           // (M_,2048) z
    const float* __restrict__ conv_w,
    const float* __restrict__ conv_b)
{
    constexpr int XS = 136;                       // padded X stride (elems)
    __shared__ __align__(16) bf16 smem[128 * XS]; // 34816 B
    const int tid  = threadIdx.x;
    const int wave = tid >> 6;
    const int lane = tid & 63;
    const int bm = blockIdx.y * 128;
    const int bn = blockIdx.x * 128;
    const int lrow = lane >> 2;
    const int lkc  = (lane & 3) * 8;
    const int wm = (wave >> 1) * 64;
    const int wn = (wave & 1) * 64;
    const int fm = lane & 15;
    const int fq = lane >> 4;

    f32x4 acc[4][4];
    #pragma unroll
    for (int i = 0; i < 4; ++i)
        #pragma unroll
        for (int j = 0; j < 4; ++j)
            acc[i][j] = (f32x4){0.f, 0.f, 0.f, 0.f};

    for (int k0 = 0; k0 < 1024; k0 += 32) {
        #pragma unroll
        for (int i = 0; i < 4; ++i) {
            int rowbase = wave * 64 + i * 16;     // wave-uniform
            int row = rowbase + lrow;
            if (rowbase < 128) {
                const bf16* ga = A + (size_t)(bm + row) * 1024 + k0 + lkc;
                __builtin_amdgcn_global_load_lds(
                    (const __attribute__((address_space(1))) void*)ga,
                    (__attribute__((address_space(3))) void*)&smem[rowbase * 32],
                    16, 0, 0);
            } else {
                const bf16* gb = Bt + (size_t)(bn + row - 128) * 1024 + k0 + lkc;
                __builtin_amdgcn_global_load_lds(
                    (const __attribute__((address_space(1))) void*)gb,
                    (__attribute__((address_space(3))) void*)&smem[4096 + (rowbase - 128) * 32],
                    16, 0, 0);
            }
        }
        __syncthreads();
        bf16x8 a[4], b[4];
        #pragma unroll
        for (int i = 0; i < 4; ++i)
            a[i] = *(const bf16x8*)&smem[(wm + i * 16 + fm) * 32 + fq * 8];
        #pragma unroll
        for (int j = 0; j < 4; ++j)
            b[j] = *(const bf16x8*)&smem[4096 + (wn + j * 16 + fm) * 32 + fq * 8];
        #pragma unroll
        for (int i = 0; i < 4; ++i)
            #pragma unroll
            for (int j = 0; j < 4; ++j)
                acc[i][j] = __builtin_amdgcn_mfma_f32_16x16x32_bf16(
                    a[i], b[j], acc[i][j], 0, 0, 0);
        __syncthreads();   // As/Bs region dead -> reusable as conv buffer
    }

    if (bn < 2048) {
        #pragma unroll
        for (int i = 0; i < 4; ++i) {
            int rowb = wm + i * 16 + fq * 4;
            #pragma unroll
            for (int j = 0; j < 4; ++j) {
                int col = wn + j * 16 + fm;
                #pragma unroll
                for (int r = 0; r < 4; ++r)
                    smem[(rowb + r) * XS + col] = __float2bfloat16(acc[i][j][r]);
            }
        }
        __syncthreads();
        {
            int col = tid & 127;
            int seq = tid >> 7;                   // 0 or 1
            int gcol = bn + col;
            float4 cw = *(const float4*)&conv_w[gcol * 4];
            float cb = conv_b[gcol];
            float w0 = 0.f, w1 = 0.f, w2 = 0.f;
            int base = seq * 64;
            for (int t = 0; t < 64; ++t) {
                int idx = (base + t) * XS + col;
                float cur = __bfloat162float(smem[idx]);
                float cacc = cb;
                cacc = fmaf(w0, cw.x, cacc); cacc = fmaf(w1, cw.y, cacc);
                cacc = fmaf(w2, cw.z, cacc); cacc = fmaf(cur, cw.w, cacc);
                smem[idx] = __float2bfloat16(__fdividef(cacc, 1.f + __expf(-cacc)));
                w0 = w1; w1 = w2; w2 = cur;
            }
        }
        __syncthreads();
        #pragma unroll
        for (int it = 0; it < 8; ++it) {
            int g = it * 256 + tid;               // 2048 groups of 8
            int row = g >> 4;
            int cg = (g & 15) * 8;
            bf16x8 v = *(const bf16x8*)&smem[row * XS + cg];
            *(bf16x8*)&xcb[(size_t)(bm + row) * 2048 + bn + cg] = v;
        }
    } else {
        #pragma unroll
        for (int i = 0; i < 4; ++i) {
            int rowb = bm + wm + i * 16 + fq * 4;
            #pragma unroll
            for (int j = 0; j < 4; ++j) {
                int col = bn - 2048 + wn + j * 16 + fm;
                #pragma unroll
                for (int r = 0; r < 4; ++r)
                    zb[(size_t)(rowb + r) * 2048 + col] =
                        __float2bfloat16(acc[i][j][r]);
            }
        }
    }
}

// ---------------------------------------------------------------------------
// Split-K partial reduction: out_bf16 = act(sum_p parts + bias)
// ---------------------------------------------------------------------------
template<int P, int RELU, int NCOL>
__global__ __launch_bounds__(256) void redp_kernel(
    const float* __restrict__ parts, int stride,
    const float* __restrict__ bias, bf16* __restrict__ out)
{
    int i4 = blockIdx.x * 256 + threadIdx.x;
    int i = i4 * 4;
    float4 s = *(const float4*)(parts + i);
    #pragma unroll
    for (int p = 1; p < P; ++p) {
        float4 v = *(const float4*)(parts + (size_t)p * stride + i);
        s.x += v.x; s.y += v.y; s.z += v.z; s.w += v.w;
    }
    if (NCOL > 0) {
        int c = i & (NCOL - 1);
        s.x += bias[c]; s.y += bias[c + 1]; s.z += bias[c + 2]; s.w += bias[c + 3];
    }
    if (RELU) {
        s.x = fmaxf(s.x, 0.f); s.y = fmaxf(s.y, 0.f);
        s.z = fmaxf(s.z, 0.f); s.w = fmaxf(s.w, 0.f);
    }
    bf16 o[4] = {__float2bfloat16(s.x), __float2bfloat16(s.y),
                 __float2bfloat16(s.z), __float2bfloat16(s.w)};
    *(short4*)&out[i] = *(short4*)o;
}

// reduce P split-K partials of proj -> proj fp32 + projb bf16
template<int P>
__global__ __launch_bounds__(256) void reduce_proj_kernel(
    const float* __restrict__ parts, float* __restrict__ proj,
    bf16* __restrict__ projb)
{
    int i = blockIdx.x * 256 + threadIdx.x;     // < 393216
    float s = parts[i];
    #pragma unroll
    for (int p = 1; p < P; ++p) s += parts[(size_t)p * 393216 + i];
    proj[i] = s;
    projb[i] = __float2bfloat16(s);
}

// ---------------------------------------------------------------------------
// prep: concat->bf16 (blocks [0,4096)), W_out straight bf16 convert (blocks
// [4096,6144) — no transpose; it is the GEMM-B operand for the Wc fold),
// and 4 weight transposes fp32(K,N)->bf16(N,K) (blocks [6144,7104)).
// ---------------------------------------------------------------------------
__global__ __launch_bounds__(256) void prep_kernel(
    const float* __restrict__ sp, const float* __restrict__ tp,
    bf16* __restrict__ xb,
    const float* __restrict__ W_out, bf16* __restrict__ Wob,
    const float* __restrict__ W_x,   bf16* __restrict__ WxT,
    const float* __restrict__ W_dt,  bf16* __restrict__ WdT,
    const float* __restrict__ W1,    bf16* __restrict__ W1T,
    const float* __restrict__ W2,    bf16* __restrict__ W2T)
{
    __shared__ float tile[32][33];
    const int b = blockIdx.x;
    const int tid = threadIdx.x;
    if (b < 4096) {
        int idx = b * 256 + tid;
        int row = idx >> 8;
        int c4 = (idx & 255) * 4;
        const float* src = (c4 < 512) ? (sp + (size_t)row * 512 + c4)
                                      : (tp + (size_t)row * 512 + (c4 - 512));
        float4 v = *(const float4*)src;
        bf16* dst = xb + (size_t)row * 1024 + c4;
        dst[0] = __float2bfloat16(v.x); dst[1] = __float2bfloat16(v.y);
        dst[2] = __float2bfloat16(v.z); dst[3] = __float2bfloat16(v.w);
        return;
    }
    if (b < 6144) {
        // W_out (2048x1024 fp32) -> Wob (bf16, same layout)
        int idx = (b - 4096) * 1024 + tid * 4;
        float4 v = *(const float4*)(W_out + idx);
        bf16 o[4] = {__float2bfloat16(v.x), __float2bfloat16(v.y),
                     __float2bfloat16(v.z), __float2bfloat16(v.w)};
        *(short4*)&Wob[idx] = *(short4*)o;
        return;
    }
    const float* W; bf16* Wt; int K, N, tb;
    if      (b < 6336) { W = W_x;  Wt = WxT; K = 2048; N = 96;   tb = b - 6144; }
    else if (b < 6464) { W = W_dt; Wt = WdT; K = 64;   N = 2048; tb = b - 6336; }
    else if (b < 6976) { W = W1;   Wt = W1T; K = 1024; N = 512;  tb = b - 6464; }
    else               { W = W2;   Wt = W2T; K = 512;  N = 256;  tb = b - 6976; }
    int nb = N / 32;
    int bn = (tb % nb) * 32, bk = (tb / nb) * 32;
    int tx = tid & 31, ty = tid >> 5;
    #pragma unroll
    for (int i = 0; i < 32; i += 8)
        tile[ty + i][tx] = W[(size_t)(bk + ty + i) * N + bn + tx];
    __syncthreads();
    #pragma unroll
    for (int i = 0; i < 32; i += 8)
        Wt[(size_t)(bn + ty + i) * K + bk + tx] = __float2bfloat16(tile[tx][ty + i]);
}

// ---------------------------------------------------------------------------
// Selective scan. One thread per (b, d); h[16] in registers; sequential t.
// Writes gated y IN-PLACE over xcy. B/C rows staged in LDS.
// ---------------------------------------------------------------------------
__global__ __launch_bounds__(256) void scan_kernel(
    const float* __restrict__ proj,   // (M_, 96): [64:80)=Bs, [80:96)=Cs
    const bf16*  __restrict__ dtb,    // (M_, DI) softplus dt (bf16)
    bf16* __restrict__ xcy,           // (M_, DI) in: xc, out: gated y
    const bf16*  __restrict__ zb,     // (M_, DI) z
    const float* __restrict__ A_log,  // (DI, 16)
    const float* __restrict__ D_skip) // (DI)
{
    __shared__ float BC[64][32];      // [t][0:16)=B, [16:32)=C
    const int tid = threadIdx.x;
    const int b = blockIdx.y;         // 0..63
    for (int i = tid; i < 64 * 32; i += 256) {
        int t = i >> 5, c = i & 31;
        BC[t][c] = proj[(size_t)(b * 64 + t) * 96 + 64 + c];
    }
    __syncthreads();

    const int d = blockIdx.x * 256 + tid;    // 0..2047
    float av[16];
    const float4* alp = (const float4*)(A_log + d * 16);
    *(float4*)&av[0]  = alp[0];
    *(float4*)&av[4]  = alp[1];
    *(float4*)&av[8]  = alp[2];
    *(float4*)&av[12] = alp[3];
    float A[16];
    #pragma unroll
    for (int n = 0; n < 16; ++n) A[n] = -__expf(av[n]);
    const float Dv = D_skip[d];
    float h[16];
    #pragma unroll
    for (int n = 0; n < 16; ++n) h[n] = 0.f;

    #pragma unroll 2
    for (int t = 0; t < T_; ++t) {
        int row = b * T_ + t;
        size_t off = (size_t)row * DI + d;
        float xv = __bfloat162float(xcy[off]);
        float dt = __bfloat162float(dtb[off]);
        float dtx = dt * xv;
        float y = 0.f;
        #pragma unroll
        for (int n = 0; n < 16; ++n) {
            float dA = __expf(dt * A[n]);
            h[n] = fmaf(dA, h[n], dtx * BC[t][n]);
            y = fmaf(h[n], BC[t][16 + n], y);
        }
        float sk = fmaf(xv, Dv, y);
        float z = __bfloat162float(zb[off]);
        float g = __fdividef(z, 1.f + __expf(-z));          // silu(z)
        xcy[off] = __float2bfloat16(sk * g);
    }
}

// ---------------------------------------------------------------------------
// Fused tail: h2 = relu(reduce_P(p6) + b2); out = h2 @ W3 + b3.
// ---------------------------------------------------------------------------
template<int P>
__global__ __launch_bounds__(256) void head_kernel(
    const float* __restrict__ p6, int stride,
    const float* __restrict__ b2,
    const float* __restrict__ W3, const float* __restrict__ b3,
    float* __restrict__ out)
{
    int row = blockIdx.x * 4 + (threadIdx.x >> 6);
    int lane = threadIdx.x & 63;
    float acc[6] = {0.f, 0.f, 0.f, 0.f, 0.f, 0.f};
    #pragma unroll
    for (int kk = 0; kk < 4; ++kk) {
        int c = lane + kk * 64;
        size_t off = (size_t)row * 256 + c;
        float s = p6[off];
        #pragma unroll
        for (int p = 1; p < P; ++p) s += p6[(size_t)p * stride + off];
        s = fmaxf(s + b2[c], 0.f);
        #pragma unroll
        for (int n = 0; n < 6; ++n) acc[n] = fmaf(s, W3[c * 6 + n], acc[n]);
    }
    #pragma unroll
    for (int n = 0; n < 6; ++n) {
        float v = acc[n];
        #pragma unroll
        for (int off = 32; off > 0; off >>= 1) v += __shfl_down(v, off);
        if (lane == 0) out[(size_t)row * 6 + n] = v + b3[n];
    }
}

// ---------------------------------------------------------------------------
extern "C" void kernel_launch(void* const* d_in, const int* in_sizes, int n_in,
                              void* d_out, int out_size, void* d_ws, size_t ws_size,
                              hipStream_t stream)
{
    const float* spatial  = (const float*)d_in[0];
    const float* temporal = (const float*)d_in[1];
    const float* W_in     = (const float*)d_in[2];
    const float* conv_w   = (const float*)d_in[3];
    const float* conv_b   = (const float*)d_in[4];
    const float* W_x      = (const float*)d_in[5];
    const float* W_dt     = (const float*)d_in[6];
    const float* b_dt     = (const float*)d_in[7];
    const float* A_log    = (const float*)d_in[8];
    const float* D_skip   = (const float*)d_in[9];
    const float* W_out    = (const float*)d_in[10];
    const float* W1       = (const float*)d_in[11];
    const float* b1       = (const float*)d_in[12];
    const float* W2       = (const float*)d_in[13];
    const float* b2       = (const float*)d_in[14];
    const float* W3       = (const float*)d_in[15];
    const float* b3       = (const float*)d_in[16];
    float* out = (float*)d_out;

    // Workspace layout (bytes), total 113,377,280.
    // +0        : xcb (M_,2048 bf16, 16 MiB) = scan's in-place y = G4' A.
    // +33554432 : 32 MiB time-shared: dtb (bf16 16 MiB, until scan) ->
    //             p5 (4x8 MiB, G4' partials) -> p6 (4x4 MiB, G6 partials).
    char* w = (char*)d_ws;
    bf16*  xcb  = (bf16*)(w);                 // (M_,2048) xc -> y (in-place)
    bf16*  zb   = (bf16*)(w + 16777216);      // (M_,2048) 16 MiB
    bf16*  dtb  = (bf16*)(w + 33554432);      // (M_,2048) bf16
    float* p5   = (float*)(w + 33554432);     // 4x(M_,512) fp32
    float* p6   = (float*)(w + 33554432);     // 4x(M_,256) fp32
    bf16*  xb   = (bf16*)(w + 67108864);      // (M_,1024) 8 MiB
    bf16*  WinT = (bf16*)(w + 75497472);      // (4096,1024) 8 MiB
    bf16*  WcT  = (bf16*)(w + 83886080);      // (512,2048) 2 MiB (folded Wout@W1 ^T)
    bf16*  W1T  = (bf16*)(w + 88080384);      // (512,1024) 1 MiB
    bf16*  W2T  = (bf16*)(w + 89128960);      // (256,512) 256 KiB
    bf16*  WxT  = (bf16*)(w + 89391104);      // (96,2048) 384 KiB
    bf16*  WdT  = (bf16*)(w + 89784320);      // (2048,64) 256 KiB
    float* projp= (float*)(w + 90046464);     // 8x(M_,96) partials 12 MiB
    float* proj = (float*)(w + 102629376);    // (M_,96) fp32 1.5 MiB
    bf16*  projb= (bf16*)(w + 104202240);     // (M_,96) bf16 768 KiB
    bf16*  h1   = (bf16*)(w + 104988672);     // (M_,512) 4 MiB
    bf16*  Wob  = (bf16*)(w + 109182976);     // (2048,1024) 4 MiB; end 113377280

    dim3 blk(256);
    // 0. prep also transposes W_in via the generic branch? No — W_in uses the
    // dedicated transpose loop below (it kept its own blocks in prior rounds;
    // now folded into the same kernel via extra blocks): W_in is (1024,4096),
    // handled by a second prep launch to keep block math simple.
    // (W_in transpose: 128x32 tiles -> 4096 blocks, same 32x32 tile kernel.)

    // 1a. concat + Wob convert + W_x/W_dt/W1/W2 transposes (7104 blocks)
    prep_kernel<<<dim3(7104), blk, 0, stream>>>(
        spatial, temporal, xb, W_out, Wob, W_x, WxT, W_dt, WdT,
        W1, W1T, W2, W2T);

    // 1b. W_in transpose (1024,4096)->(4096,1024), reuse generic GEMM-free
    //     transpose by calling prep-style tile kernel: implemented via
    //     gemm-free path below (separate kernel not needed — use a small
    //     dedicated launch of the same tile loop through prep is complex;
    //     instead use a simple standalone transpose):
    {
        // standalone W_in transpose kernel, declared inline via lambda-less
        // dispatch: see tconv_win below.
        extern __global__ void tconv_win(const float*, bf16*);
        tconv_win<<<dim3(4096), blk, 0, stream>>>(W_in, WinT);
    }

    // 2. Wc fold: WcT = W1T @ Wob^T   (512 x 2048, K=1024), 128 blocks
    gemm_mfma<0, 1, 1, 128, 64><<<dim3(32, 4), blk, 0, stream>>>(
        W1T, 1024, Wob, 1024, WcT, 2048, nullptr, 2048, 1024);

    // 3. G1 (+fused conv/silu)
    gemm_g1_conv<<<dim3(32, 32), blk, 0, stream>>>(
        xb, WinT, xcb, zb, conv_w, conv_b);

    // 4. G2: proj partials = xc @ W_x   (4096 x 96, K=2048), split-K x8
    gemm_mfma<0, 0, 8, 128, 128><<<dim3(1, 32, 8), blk, 0, stream>>>(
        xcb, 2048, WxT, 2048, projp, 96, nullptr, 96, 2048);

    // 5. reduce partials -> proj (fp32) + projb (bf16)
    reduce_proj_kernel<8><<<dim3(1536), blk, 0, stream>>>(projp, proj, projb);

    // 6. G3: dt = softplus(proj[:, :64] @ W_dt + b_dt) -> bf16 dtb
    gemm_mfma<2, 1, 1, 128, 64><<<dim3(32, 32), blk, 0, stream>>>(
        projb, 96, WdT, 64, dtb, 2048, b_dt, 2048, 64);

    // 7. Selective scan + skip + gating, y in-place over xcb
    scan_kernel<<<dim3(8, 64), blk, 0, stream>>>(
        proj, dtb, xcb, zb, A_log, D_skip);

    // 8. G4': p5 = y @ Wc   (4096 x 512, K=2048), split-K x4 -> 512 blocks
    gemm_mfma<0, 0, 4, 128, 128><<<dim3(4, 32, 4), blk, 0, stream>>>(
        xcb, 2048, WcT, 2048, p5, 512, nullptr, 512, 2048);

    // 9. h1 = relu(reduce(p5) + b1) -> bf16
    redp_kernel<4, 1, 512><<<dim3(2048), blk, 0, stream>>>(
        p5, 2097152, b1, h1);

    // 10. G6: p6 = h1 @ W2   (4096 x 256, K=512), split-K x4 -> 256 blocks
    gemm_mfma<0, 0, 4, 128, 128><<<dim3(2, 32, 4), blk, 0, stream>>>(
        h1, 512, W2T, 512, p6, 256, nullptr, 256, 512);

    // 11. fused: out = relu(reduce(p6) + b2) @ W3 + b3
    head_kernel<4><<<dim3(1024), blk, 0, stream>>>(
        p6, 1048576, b2, W3, b3, out);
}

// ---------------------------------------------------------------------------
// Standalone W_in transpose: (1024,4096) fp32 -> (4096,1024) bf16.
// 32x32 LDS tiles; 4096 blocks (128 col-tiles x 32 row-tiles).
// ---------------------------------------------------------------------------
__global__ __launch_bounds__(256) void tconv_win(
    const float* __restrict__ W, bf16* __restrict__ Wt)
{
    __shared__ float tile[32][33];
    int tb = blockIdx.x;
    int bn = (tb & 127) * 32;         // col tile (N=4096)
    int bk = (tb >> 7) * 32;          // row tile (K=1024)
    int tx = threadIdx.x & 31, ty = threadIdx.x >> 5;
    #pragma unroll
    for (int i = 0; i < 32; i += 8)
        tile[ty + i][tx] = W[(size_t)(bk + ty + i) * 4096 + bn + tx];
    __syncthreads();
    #pragma unroll
    for (int i = 0; i < 32; i += 8)
        Wt[(size_t)(bn + ty + i) * 1024 + bk + tx] = __float2bfloat16(tile[tx][ty + i]);
}